// Round 11
// baseline (304.897 us; speedup 1.0000x reference)
//
#include <hip/hip_runtime.h>
#include <stdint.h>

#define DD   512
#define EE   8

typedef __bf16 bf16x8 __attribute__((ext_vector_type(8)));
typedef float  f32x4  __attribute__((ext_vector_type(4)));
typedef unsigned short u16x8 __attribute__((ext_vector_type(8)));

__device__ __forceinline__ unsigned short f2bf(float f) {  // RTNE
    union { float f; unsigned int i; } v; v.f = f;
    unsigned int x = v.i;
    x += 0x7fffu + ((x >> 16) & 1u);
    return (unsigned short)(x >> 16);
}
__device__ __forceinline__ void gload_lds16(const void* g, void* l) {
    __builtin_amdgcn_global_load_lds(
        (const __attribute__((address_space(1))) unsigned int*)g,
        (__attribute__((address_space(3))) unsigned int*)l, 16, 0, 0);
}
__device__ __forceinline__ f32x4 mfma_bf16(bf16x8 a, bf16x8 b, f32x4 c) {
    return __builtin_amdgcn_mfma_f32_16x16x32_bf16(a, b, c, 0, 0, 0);
}

// ---------- K0r: W_root (f32) [k][n] -> WrTh (bf16) [n][k] ----------
__global__ __launch_bounds__(256) void k_wtr(
    const float* __restrict__ W_root, unsigned short* __restrict__ WrTh)
{
    __shared__ unsigned short tile[64][65];
    int tl = blockIdx.x, tr = tl >> 3, tc = tl & 7;   // 64 tiles
    int t = threadIdx.x;
    #pragma unroll
    for (int j = 0; j < 16; j++) {
        int i2 = t + j * 256; int r = i2 >> 6, c = i2 & 63;
        tile[r][c] = f2bf(W_root[(size_t)(tr * 64 + r) * DD + tc * 64 + c]);
    }
    __syncthreads();
    #pragma unroll
    for (int j = 0; j < 16; j++) {
        int i2 = t + j * 256; int r = i2 >> 6, c = i2 & 63;
        WrTh[(size_t)(tc * 64 + r) * DD + tr * 64 + c] = tile[c][r];
    }
}

// ---------- K0a: W_leaf (f32) [e][d][h] -> WlT (bf16) [e][h][d] ----------
__global__ __launch_bounds__(256) void k_trW(
    const float* __restrict__ W_leaf, unsigned short* __restrict__ WlT)
{
    __shared__ unsigned short tile[64][65];
    int bid = blockIdx.x;            // 8 mats * 64 tiles
    int e = bid >> 6;
    int tl = bid & 63, tr = tl >> 3, tc = tl & 7;
    const float* src = W_leaf + (size_t)e * DD * DD;
    unsigned short* dst = WlT + (size_t)e * DD * DD;
    int t = threadIdx.x;
    #pragma unroll
    for (int j = 0; j < 16; j++) {
        int i2 = t + j * 256; int r = i2 >> 6, c = i2 & 63;
        tile[r][c] = f2bf(src[(size_t)(tr * 64 + r) * DD + tc * 64 + c]);
    }
    __syncthreads();
    #pragma unroll
    for (int j = 0; j < 16; j++) {
        int i2 = t + j * 256; int r = i2 >> 6, c = i2 & 63;
        dst[(size_t)(tc * 64 + r) * DD + tr * 64 + c] = tile[c][r];
    }
}

// ---------- K0b: W_ldec (f32) [e][d][o] -> WldT (bf16) [e][16][512], zero-padded ----------
__global__ __launch_bounds__(256) void k_trpad(
    const float* __restrict__ W_ldec, unsigned short* __restrict__ WldT)
{
    int idx = blockIdx.x * 256 + threadIdx.x;      // 65536
    int e = idx >> 13, rem = idx & 8191;
    int o = rem >> 9, k = rem & 511;
    unsigned short v = 0;
    if (o < 8) v = f2bf(W_ldec[((size_t)e * DD + k) * EE + o]);
    WldT[idx] = v;
}

// ---------- K0c: W_dec (f32) [d][o] -> WdT (bf16) [16][512], zero-padded ----------
__global__ __launch_bounds__(256) void k_trdec(
    const float* __restrict__ W_dec, unsigned short* __restrict__ WdT)
{
    int idx = blockIdx.x * 256 + threadIdx.x;      // 8192
    int o = idx >> 9, k = idx & 511;
    WdT[idx] = (o < 8) ? f2bf(W_dec[(size_t)k * EE + o]) : (unsigned short)0;
}

// ---------- K1: bf16 MFMA root GEMM (round-8 loop); half-tile epilogue, 17.4KB LDS ----------
__global__ __launch_bounds__(256) void k_root(
    const float* __restrict__ x,
    const unsigned short* __restrict__ WrTh,
    const float* __restrict__ b_root,
    const unsigned short* __restrict__ WdT,
    unsigned short* __restrict__ hbuf,
    float* __restrict__ logit_part)          // [4][65536][8], p = cb
{
    __shared__ unsigned short smem[8704];        // 17408 B: loop lsA+lsB; epi: 64x136 lh half
    unsigned short* lsA = smem;                  // [128][32] u16
    unsigned short* lsB = smem + 4096;           // [128][32] u16

    int bid = blockIdx.x;                         // 2048 = 512 mb * 4 cb
    int mb = (bid >> 5) * 8 + (bid & 7);          // XCD-swizzled: 4 cb of same mb on one XCD
    int cb = (bid >> 3) & 3;
    int m0 = mb * 128, n0 = cb * 128;

    int t = threadIdx.x;
    int wid = t >> 6, lane = t & 63;
    int wr = wid >> 1, wc = wid & 1;
    int l15 = lane & 15, l4 = lane >> 4;

    // A: reg-staged f32 -> bf16 (row t>>1, 16 k at (t&1)*16)
    int ar = t >> 1, ah16 = (t & 1) * 16;
    const float* pA = x + (size_t)(m0 + ar) * DD + ah16;
    // B: global_load_lds direct (2 issues per K-step), linear
    const unsigned short* srcB0 = WrTh + (size_t)(n0 + (t >> 2)) * DD + (t & 3) * 8;
    const unsigned short* srcB1 = srcB0 + (size_t)64 * DD;
    unsigned short* dB0 = &lsB[t * 8];
    unsigned short* dB1 = &lsB[2048 + t * 8];

    f32x4 acc[4][4];
    #pragma unroll
    for (int m = 0; m < 4; m++)
        #pragma unroll
        for (int n = 0; n < 4; n++) acc[m][n] = (f32x4){0.f, 0.f, 0.f, 0.f};

    for (int k0 = 0; k0 < DD; k0 += 32) {
        const float4* pAv = (const float4*)(pA + k0);
        float4 v0 = pAv[0], v1 = pAv[1], v2 = pAv[2], v3 = pAv[3];
        float vv[16] = {v0.x,v0.y,v0.z,v0.w, v1.x,v1.y,v1.z,v1.w,
                        v2.x,v2.y,v2.z,v2.w, v3.x,v3.y,v3.z,v3.w};
        bf16x8 hv0, hv1;
        #pragma unroll
        for (int j = 0; j < 8; j++) { hv0[j] = (__bf16)vv[j]; hv1[j] = (__bf16)vv[8 + j]; }
        __syncthreads();                      // previous compute done
        *(bf16x8*)&lsA[ar * 32 + ah16]     = hv0;
        *(bf16x8*)&lsA[ar * 32 + ah16 + 8] = hv1;
        gload_lds16(srcB0 + k0, dB0);
        gload_lds16(srcB1 + k0, dB1);
        __syncthreads();                      // stage complete

        bf16x8 fa[4], fb[4];
        #pragma unroll
        for (int m = 0; m < 4; m++)
            fa[m] = *(const bf16x8*)&lsA[(wr * 64 + m * 16 + l15) * 32 + l4 * 8];
        #pragma unroll
        for (int n = 0; n < 4; n++)
            fb[n] = *(const bf16x8*)&lsB[(wc * 64 + n * 16 + l15) * 32 + l4 * 8];
        #pragma unroll
        for (int m = 0; m < 4; m++)
            #pragma unroll
            for (int n = 0; n < 4; n++)
                acc[m][n] = mfma_bf16(fa[m], fb[n], acc[m][n]);
    }
    __syncthreads();     // loop buffers dead; smem becomes lh half [64][136]

    float bcol[4];
    #pragma unroll
    for (int n = 0; n < 4; n++) bcol[n] = b_root[n0 + wc * 64 + n * 16 + l15];

    #pragma unroll
    for (int hh = 0; hh < 2; hh++) {
        // epi 1: waves owning this row-half deposit relu(acc+b) as bf16
        if (wr == hh) {
            #pragma unroll
            for (int n = 0; n < 4; n++) {
                int coll = wc * 64 + n * 16 + l15;
                #pragma unroll
                for (int m = 0; m < 4; m++) {
                    int rl = m * 16 + l4 * 4;
                    #pragma unroll
                    for (int i = 0; i < 4; i++) {
                        float v = acc[m][n][i] + bcol[n];
                        v = v > 0.f ? v : 0.f;
                        smem[(rl + i) * 136 + coll] = f2bf(v);
                    }
                }
            }
        }
        __syncthreads();

        // epi 2a: vectorized h store (64 rows x 128 cols)
        {
            int r = t >> 2, c0s = (t & 3) * 32;
            unsigned short* dst = hbuf + (size_t)(m0 + hh * 64 + r) * DD + n0 + c0s;
            #pragma unroll
            for (int j = 0; j < 4; j++)
                *(u16x8*)(dst + j * 8) = *(const u16x8*)&smem[r * 136 + c0s + j * 8];
        }

        // epi 2b: logit partial = lh_half @ W_dec[n0:n0+128][:] via MFMA
        f32x4 acc2 = (f32x4){0.f, 0.f, 0.f, 0.f};
        #pragma unroll
        for (int kk = 0; kk < 4; kk++) {
            bf16x8 bb = *(const bf16x8*)(WdT + (size_t)l15 * DD + n0 + kk * 32 + l4 * 8);
            bf16x8 aa = *(const bf16x8*)&smem[(wid * 16 + l15) * 136 + kk * 32 + l4 * 8];
            acc2 = mfma_bf16(aa, bb, acc2);
        }
        if (l15 < 8) {
            #pragma unroll
            for (int i = 0; i < 4; i++) {
                int rowg = m0 + hh * 64 + wid * 16 + l4 * 4 + i;
                logit_part[((size_t)cb * 65536 + rowg) * 8 + l15] = acc2[i];
            }
        }
        __syncthreads();     // protect lh before next half overwrites
    }
}

// ---------- K2: dec = softmax(sum of 4 partials, f64 sum); route; gap-flag ----------
__global__ __launch_bounds__(256) void k_dec(
    const float* __restrict__ logit_part,
    const float* __restrict__ b_dec,
    float* __restrict__ out,
    int* __restrict__ route,
    int* __restrict__ meta,
    int* __restrict__ rescue_list)
{
    int b = blockIdx.x * 256 + threadIdx.x;
    double lg[8];
    #pragma unroll
    for (int o = 0; o < 8; o++) lg[o] = (double)b_dec[o];
    #pragma unroll
    for (int ppp = 0; ppp < 4; ppp++) {        // fixed order: deterministic
        #pragma unroll
        for (int o = 0; o < 8; o++)
            lg[o] += (double)logit_part[((size_t)ppp * 65536 + b) * 8 + o];
    }
    double mx = -1e300, mx2 = -1e300; int idx = 0;
    #pragma unroll
    for (int o = 0; o < 8; o++) {
        if (lg[o] > mx) { mx2 = mx; mx = lg[o]; idx = o; }
        else if (lg[o] > mx2) mx2 = lg[o];
    }
    float ev[8], s = 0.f;
    #pragma unroll
    for (int o = 0; o < 8; o++) { ev[o] = expf((float)(lg[o] - mx)); s += ev[o]; }
    float inv = 1.f / s;
    float4 o0, o1;
    o0.x = ev[0]*inv; o0.y = ev[1]*inv; o0.z = ev[2]*inv; o0.w = ev[3]*inv;
    o1.x = ev[4]*inv; o1.y = ev[5]*inv; o1.z = ev[6]*inv; o1.w = ev[7]*inv;
    float4* op = (float4*)(out + (size_t)b * 16);
    op[0] = o0; op[1] = o1;
    route[b] = idx;
    if (mx - mx2 < 3e-3) {                     // near-tie (~8 sigma of bf16-GEMM logit err)
        int pos = atomicAdd(&meta[27], 1);
        if (pos < 8192) rescue_list[pos] = b;
    }
}

// ---------- K2b: exact f64 rescue (dec + route) ----------
__global__ __launch_bounds__(256) void k_rescue(
    const float* __restrict__ x,
    const float* __restrict__ W_root,
    const float* __restrict__ b_root,
    const float* __restrict__ W_dec,
    const float* __restrict__ b_dec,
    const int* __restrict__ rescue_list,
    const int* __restrict__ meta,
    float* __restrict__ out,
    int* __restrict__ route)
{
    int nresc = min(meta[27], 8192);
    if ((int)blockIdx.x >= nresc) return;
    int row = rescue_list[blockIdx.x];
    int t = threadIdx.x;

    __shared__ float xr[512];
    __shared__ double red[4][8];
    xr[t * 2]     = x[(size_t)row * DD + t * 2];
    xr[t * 2 + 1] = x[(size_t)row * DD + t * 2 + 1];
    __syncthreads();

    int d0 = t, d1 = t + 256;
    double a0 = 0.0, a1 = 0.0;
    for (int k = 0; k < DD; k++) {
        double xv = (double)xr[k];
        a0 += xv * (double)W_root[(size_t)k * DD + d0];
        a1 += xv * (double)W_root[(size_t)k * DD + d1];
    }
    double h0 = fmax(a0 + (double)b_root[d0], 0.0);
    double h1 = fmax(a1 + (double)b_root[d1], 0.0);
    double so[8];
    #pragma unroll
    for (int o = 0; o < 8; o++)
        so[o] = h0 * (double)W_dec[d0 * 8 + o] + h1 * (double)W_dec[d1 * 8 + o];
    #pragma unroll
    for (int d = 1; d < 64; d <<= 1)
        #pragma unroll
        for (int o = 0; o < 8; o++) so[o] += __shfl_xor(so[o], d, 64);
    if ((t & 63) == 0) {
        #pragma unroll
        for (int o = 0; o < 8; o++) red[t >> 6][o] = so[o];
    }
    __syncthreads();
    if (t == 0) {
        double lg[8]; double mx = -1e300; int idx = 0;
        #pragma unroll
        for (int o = 0; o < 8; o++) {
            lg[o] = red[0][o] + red[1][o] + red[2][o] + red[3][o] + (double)b_dec[o];
            if (lg[o] > mx) { mx = lg[o]; idx = o; }
        }
        double ev[8], s = 0.0;
        #pragma unroll
        for (int o = 0; o < 8; o++) { ev[o] = exp(lg[o] - mx); s += ev[o]; }
        double inv = 1.0 / s;
        float4 o0, o1;
        o0.x = (float)(ev[0]*inv); o0.y = (float)(ev[1]*inv);
        o0.z = (float)(ev[2]*inv); o0.w = (float)(ev[3]*inv);
        o1.x = (float)(ev[4]*inv); o1.y = (float)(ev[5]*inv);
        o1.z = (float)(ev[6]*inv); o1.w = (float)(ev[7]*inv);
        float4* op = (float4*)(out + (size_t)row * 16);
        op[0] = o0; op[1] = o1;
        route[row] = idx;
    }
}

// ---------- K2c: count routes — ballot-aggregated, 8 atomics/block ----------
__global__ __launch_bounds__(256) void k_count(
    const int* __restrict__ route, int* __restrict__ meta)
{
    __shared__ int wcnt[4][8];
    int b = blockIdx.x * 256 + threadIdx.x;
    int e = route[b];
    int lane = threadIdx.x & 63, wv = threadIdx.x >> 6;
    #pragma unroll
    for (int ex = 0; ex < 8; ex++) {
        unsigned long long m = __ballot(e == ex);
        if (lane == 0) wcnt[wv][ex] = __popcll(m);
    }
    __syncthreads();
    if (threadIdx.x < 8) {
        int ex = threadIdx.x;
        atomicAdd(&meta[ex], wcnt[0][ex] + wcnt[1][ex] + wcnt[2][ex] + wcnt[3][ex]);
    }
}

// ---------- K3: scan ----------
__global__ void k_scan(int* __restrict__ meta)
{
    if (threadIdx.x == 0 && blockIdx.x == 0) {
        int run = 0, rb = 0;
        for (int e = 0; e < 8; e++) {
            int c = meta[e];
            meta[16 + e] = run;
            meta[8 + e]  = run;
            int n = (c + 127) >> 7;
            for (int j = 0; j < n; j++) meta[32 + rb + j] = e | (j << 8);
            rb += n;
            run += n << 7;
        }
        meta[24] = rb;
    }
}

// ---------- K4: scatter — ballot-ranked, 8 atomics/block ----------
__global__ __launch_bounds__(256) void k_scatter(
    const int* __restrict__ route, int* __restrict__ meta, int* __restrict__ rows_list)
{
    __shared__ int wcnt[4][8];
    __shared__ int wbase[4][8];
    int b = blockIdx.x * 256 + threadIdx.x;
    int e = route[b];
    int lane = threadIdx.x & 63, wv = threadIdx.x >> 6;
    unsigned long long mymask = 0;
    #pragma unroll
    for (int ex = 0; ex < 8; ex++) {
        unsigned long long m = __ballot(e == ex);
        if (e == ex) mymask = m;
        if (lane == 0) wcnt[wv][ex] = __popcll(m);
    }
    int myrank = __popcll(mymask & ((1ULL << lane) - 1ULL));
    __syncthreads();
    if (threadIdx.x < 8) {
        int ex = threadIdx.x;
        int c0 = wcnt[0][ex], c1 = wcnt[1][ex], c2 = wcnt[2][ex], c3 = wcnt[3][ex];
        int base = atomicAdd(&meta[8 + ex], c0 + c1 + c2 + c3);
        wbase[0][ex] = base;
        wbase[1][ex] = base + c0;
        wbase[2][ex] = base + c0 + c1;
        wbase[3][ex] = base + c0 + c1 + c2;
    }
    __syncthreads();
    rows_list[wbase[wv][e] + myrank] = b;
}

// ---------- K5: grouped leaf GEMM (round-8 loop); half-tile epilogue, 17.4KB LDS ----------
__global__ __launch_bounds__(256) void k_gemm2(
    const unsigned short* __restrict__ hbuf,
    const unsigned short* __restrict__ WlT,
    const float* __restrict__ b_leaf,
    const unsigned short* __restrict__ WldT,
    const int* __restrict__ rows_list,
    const int* __restrict__ meta,
    float* __restrict__ ldec_part)           // [4][65536][8]
{
    __shared__ unsigned short smem[8704];        // 17408 B: loop lsA+lsB; epi: 64x136 lh half
    unsigned short* lsA = smem;
    unsigned short* lsB = smem + 4096;

    int bid = blockIdx.x;
    int rbid = (bid >> 5) * 8 + (bid & 7);
    int cb = (bid >> 3) & 3;
    if (rbid >= meta[24]) return;
    int pk = meta[32 + rbid];
    int e = pk & 255, lrb = pk >> 8;
    int poff_e = meta[16 + e], cnt_e = meta[e];
    int n0 = cb * 128;

    int t = threadIdx.x;
    int wid = t >> 6, lane = t & 63;
    int wr = wid >> 1, wc = wid & 1;
    int l15 = lane & 15, l4 = lane >> 4;

    int slot0 = poff_e + lrb * 128 + (t >> 2);
    int slot1 = slot0 + 64;
    int lastv = poff_e + cnt_e - 1;
    int grow0 = rows_list[min(slot0, lastv)];    // clamp pad slots (idempotent recompute)
    int grow1 = rows_list[min(slot1, lastv)];
    const unsigned short* srcA0 = hbuf + (size_t)grow0 * DD + (t & 3) * 8;
    const unsigned short* srcA1 = hbuf + (size_t)grow1 * DD + (t & 3) * 8;
    const unsigned short* srcB0 = WlT + (size_t)e * DD * DD + (size_t)(n0 + (t >> 2)) * DD + (t & 3) * 8;
    const unsigned short* srcB1 = srcB0 + (size_t)64 * DD;
    unsigned short* dA0 = &lsA[t * 8];
    unsigned short* dA1 = &lsA[2048 + t * 8];
    unsigned short* dB0 = &lsB[t * 8];
    unsigned short* dB1 = &lsB[2048 + t * 8];

    f32x4 acc[4][4];
    #pragma unroll
    for (int m = 0; m < 4; m++)
        #pragma unroll
        for (int n = 0; n < 4; n++) acc[m][n] = (f32x4){0.f, 0.f, 0.f, 0.f};

    for (int k0 = 0; k0 < DD; k0 += 32) {
        __syncthreads();
        gload_lds16(srcA0 + k0, dA0);
        gload_lds16(srcA1 + k0, dA1);
        gload_lds16(srcB0 + k0, dB0);
        gload_lds16(srcB1 + k0, dB1);
        __syncthreads();
        bf16x8 af[4], bfr[4];
        #pragma unroll
        for (int m = 0; m < 4; m++)
            af[m] = *(const bf16x8*)&lsA[(wr * 64 + m * 16 + l15) * 32 + l4 * 8];
        #pragma unroll
        for (int n = 0; n < 4; n++)
            bfr[n] = *(const bf16x8*)&lsB[(wc * 64 + n * 16 + l15) * 32 + l4 * 8];
        #pragma unroll
        for (int m = 0; m < 4; m++)
            #pragma unroll
            for (int n = 0; n < 4; n++)
                acc[m][n] = mfma_bf16(af[m], bfr[n], acc[m][n]);
    }
    __syncthreads();     // loop buffers dead; smem becomes lh half [64][136]

    float bcol[4];
    #pragma unroll
    for (int n = 0; n < 4; n++) bcol[n] = b_leaf[(size_t)e * DD + n0 + wc * 64 + n * 16 + l15];

    #pragma unroll
    for (int hh = 0; hh < 2; hh++) {
        if (wr == hh) {
            #pragma unroll
            for (int n = 0; n < 4; n++) {
                int coll = wc * 64 + n * 16 + l15;
                #pragma unroll
                for (int m = 0; m < 4; m++) {
                    int rl = m * 16 + l4 * 4;
                    #pragma unroll
                    for (int i = 0; i < 4; i++) {
                        float v = acc[m][n][i] + bcol[n];
                        v = v > 0.f ? v : 0.f;
                        smem[(rl + i) * 136 + coll] = f2bf(v);
                    }
                }
            }
        }
        __syncthreads();

        // ldec partial = lh_half @ W_ldec[e][n0:n0+128][:] via MFMA
        f32x4 acc2 = (f32x4){0.f, 0.f, 0.f, 0.f};
        #pragma unroll
        for (int kk = 0; kk < 4; kk++) {
            bf16x8 bb = *(const bf16x8*)(WldT + ((size_t)e * 16 + l15) * DD + n0 + kk * 32 + l4 * 8);
            bf16x8 aa = *(const bf16x8*)&smem[(wid * 16 + l15) * 136 + kk * 32 + l4 * 8];
            acc2 = mfma_bf16(aa, bb, acc2);
        }
        if (l15 < 8) {
            #pragma unroll
            for (int i = 0; i < 4; i++) {
                int rl = hh * 64 + wid * 16 + l4 * 4 + i;
                int s = min(poff_e + lrb * 128 + rl, lastv);
                int brow = rows_list[s];             // pad slots: duplicate identical writes
                ldec_part[((size_t)cb * 65536 + brow) * 8 + l15] = acc2[i];
            }
        }
        __syncthreads();     // protect lh before next half overwrites
    }
}

// ---------- K6: sel softmax ----------
__global__ __launch_bounds__(256) void k_sel(
    const float* __restrict__ ldec_part,
    const int* __restrict__ route,
    const float* __restrict__ b_ldec,
    float* __restrict__ out)
{
    int b = blockIdx.x * 256 + threadIdx.x;
    int e = route[b];
    float lg[8];
    #pragma unroll
    for (int o = 0; o < 8; o++) lg[o] = b_ldec[e * 8 + o];
    #pragma unroll
    for (int p = 0; p < 4; p++) {
        const float4* ap = (const float4*)(ldec_part + ((size_t)p * 65536 + b) * 8);
        float4 a0 = ap[0], a1 = ap[1];
        lg[0]+=a0.x; lg[1]+=a0.y; lg[2]+=a0.z; lg[3]+=a0.w;
        lg[4]+=a1.x; lg[5]+=a1.y; lg[6]+=a1.z; lg[7]+=a1.w;
    }
    float mx = -1e30f;
    #pragma unroll
    for (int o = 0; o < 8; o++) mx = fmaxf(mx, lg[o]);
    float ev[8], s = 0.f;
    #pragma unroll
    for (int o = 0; o < 8; o++) { ev[o] = expf(lg[o] - mx); s += ev[o]; }
    float inv = 1.f / s;
    float4 o0, o1;
    o0.x = ev[0]*inv; o0.y = ev[1]*inv; o0.z = ev[2]*inv; o0.w = ev[3]*inv;
    o1.x = ev[4]*inv; o1.y = ev[5]*inv; o1.z = ev[6]*inv; o1.w = ev[7]*inv;
    float4* op = (float4*)(out + (size_t)b * 16 + 8);
    op[0] = o0; op[1] = o1;
}

extern "C" void kernel_launch(void* const* d_in, const int* in_sizes, int n_in,
                              void* d_out, int out_size, void* d_ws, size_t ws_size,
                              hipStream_t stream)
{
    const float* x      = (const float*)d_in[0];
    const float* W_root = (const float*)d_in[1];
    const float* b_root = (const float*)d_in[2];
    const float* W_dec  = (const float*)d_in[3];
    const float* b_dec  = (const float*)d_in[4];
    const float* W_leaf = (const float*)d_in[5];
    const float* b_leaf = (const float*)d_in[6];
    const float* W_ldec = (const float*)d_in[7];
    const float* b_ldec = (const float*)d_in[8];
    float* out = (float*)d_out;

    char* w = (char*)d_ws;
    unsigned short* hbuf       = (unsigned short*)(w);               // 67,108,864
    float*          logit_part = (float*)(w + 67108864);             //  8,388,608
    unsigned short* WlT        = (unsigned short*)(w + 75497472);    //  4,194,304
    unsigned short* WldT       = (unsigned short*)(w + 79691776);    //    131,072
    unsigned short* WdT        = (unsigned short*)(w + 79822848);    //     16,384
    float*          ldec_part  = (float*)(w + 79839232);             //  8,388,608
    int*            route      = (int*)(w + 88227840);               //    262,144
    int*            rows_list  = (int*)(w + 88489984);               //    266,240
    unsigned short* WrTh       = (unsigned short*)(w + 88756224);    //    524,288
    int*            rescue     = (int*)(w + 89280512);               //     32,768
    int*            meta       = (int*)(w + 89313280);               //      4,096
    const size_t WS_NEED = 89317376ULL;
    if (ws_size < WS_NEED) return;

    hipMemsetAsync(meta, 0, 4096, stream);

    k_wtr    <<<64,   256, 0, stream>>>(W_root, WrTh);
    k_trW    <<<512,  256, 0, stream>>>(W_leaf, WlT);
    k_trpad  <<<256,  256, 0, stream>>>(W_ldec, WldT);
    k_trdec  <<<32,   256, 0, stream>>>(W_dec, WdT);
    k_root   <<<2048, 256, 0, stream>>>(x, WrTh, b_root, WdT, hbuf, logit_part);
    k_dec    <<<256,  256, 0, stream>>>(logit_part, b_dec, out, route, meta, rescue);
    k_rescue <<<8192, 256, 0, stream>>>(x, W_root, b_root, W_dec, b_dec, rescue, meta, out, route);
    k_count  <<<256,  256, 0, stream>>>(route, meta);
    k_scan   <<<1,    64,  0, stream>>>(meta);
    k_scatter<<<256,  256, 0, stream>>>(route, meta, rows_list);
    k_gemm2  <<<2080, 256, 0, stream>>>(hbuf, WlT, b_leaf, WldT, rows_list, meta, ldec_part);
    k_sel    <<<256,  256, 0, stream>>>(ldec_part, route, b_ldec, out);
}

// Round 13
// 266.556 us; speedup vs baseline: 1.1438x; 1.1438x over previous
//
#include <hip/hip_runtime.h>
#include <stdint.h>

#define DD   512
#define EE   8

typedef __bf16 bf16x8 __attribute__((ext_vector_type(8)));
typedef float  f32x4  __attribute__((ext_vector_type(4)));
typedef unsigned short u16x8 __attribute__((ext_vector_type(8)));

__device__ __forceinline__ unsigned short f2bf(float f) {  // RTNE
    union { float f; unsigned int i; } v; v.f = f;
    unsigned int x = v.i;
    x += 0x7fffu + ((x >> 16) & 1u);
    return (unsigned short)(x >> 16);
}
__device__ __forceinline__ void gload_lds16(const void* g, void* l) {
    __builtin_amdgcn_global_load_lds(
        (const __attribute__((address_space(1))) unsigned int*)g,
        (__attribute__((address_space(3))) unsigned int*)l, 16, 0, 0);
}
__device__ __forceinline__ f32x4 mfma_bf16(bf16x8 a, bf16x8 b, f32x4 c) {
    return __builtin_amdgcn_mfma_f32_16x16x32_bf16(a, b, c, 0, 0, 0);
}

// ---------- K0r: W_root (f32) [k][n] -> WrTh (bf16) [n][k] ----------
__global__ __launch_bounds__(256) void k_wtr(
    const float* __restrict__ W_root, unsigned short* __restrict__ WrTh)
{
    __shared__ unsigned short tile[64][65];
    int tl = blockIdx.x, tr = tl >> 3, tc = tl & 7;   // 64 tiles
    int t = threadIdx.x;
    #pragma unroll
    for (int j = 0; j < 16; j++) {
        int i2 = t + j * 256; int r = i2 >> 6, c = i2 & 63;
        tile[r][c] = f2bf(W_root[(size_t)(tr * 64 + r) * DD + tc * 64 + c]);
    }
    __syncthreads();
    #pragma unroll
    for (int j = 0; j < 16; j++) {
        int i2 = t + j * 256; int r = i2 >> 6, c = i2 & 63;
        WrTh[(size_t)(tc * 64 + r) * DD + tr * 64 + c] = tile[c][r];
    }
}

// ---------- K0a: W_leaf (f32) [e][d][h] -> WlT (bf16) [e][h][d] ----------
__global__ __launch_bounds__(256) void k_trW(
    const float* __restrict__ W_leaf, unsigned short* __restrict__ WlT)
{
    __shared__ unsigned short tile[64][65];
    int bid = blockIdx.x;            // 8 mats * 64 tiles
    int e = bid >> 6;
    int tl = bid & 63, tr = tl >> 3, tc = tl & 7;
    const float* src = W_leaf + (size_t)e * DD * DD;
    unsigned short* dst = WlT + (size_t)e * DD * DD;
    int t = threadIdx.x;
    #pragma unroll
    for (int j = 0; j < 16; j++) {
        int i2 = t + j * 256; int r = i2 >> 6, c = i2 & 63;
        tile[r][c] = f2bf(src[(size_t)(tr * 64 + r) * DD + tc * 64 + c]);
    }
    __syncthreads();
    #pragma unroll
    for (int j = 0; j < 16; j++) {
        int i2 = t + j * 256; int r = i2 >> 6, c = i2 & 63;
        dst[(size_t)(tc * 64 + r) * DD + tr * 64 + c] = tile[c][r];
    }
}

// ---------- K0b: W_ldec (f32) [e][d][o] -> WldT (bf16) [e][16][512], zero-padded ----------
__global__ __launch_bounds__(256) void k_trpad(
    const float* __restrict__ W_ldec, unsigned short* __restrict__ WldT)
{
    int idx = blockIdx.x * 256 + threadIdx.x;      // 65536
    int e = idx >> 13, rem = idx & 8191;
    int o = rem >> 9, k = rem & 511;
    unsigned short v = 0;
    if (o < 8) v = f2bf(W_ldec[((size_t)e * DD + k) * EE + o]);
    WldT[idx] = v;
}

// ---------- K0c: W_dec (f32) [d][o] -> WdT (bf16) [16][512], zero-padded ----------
__global__ __launch_bounds__(256) void k_trdec(
    const float* __restrict__ W_dec, unsigned short* __restrict__ WdT)
{
    int idx = blockIdx.x * 256 + threadIdx.x;      // 8192
    int o = idx >> 9, k = idx & 511;
    WdT[idx] = (o < 8) ? f2bf(W_dec[(size_t)k * EE + o]) : (unsigned short)0;
}

// ---------- K1: bf16 MFMA root GEMM; double-buffered single-barrier K-loop ----------
// A staged as f32 via global_load_lds (XOR source/read swizzle); cvt at fragment read.
// B staged bf16 linear (r8 form). One __syncthreads per K-step.
__global__ __launch_bounds__(256) void k_root(
    const float* __restrict__ x,
    const unsigned short* __restrict__ WrTh,
    const float* __restrict__ b_root,
    const unsigned short* __restrict__ WdT,
    unsigned short* __restrict__ hbuf,
    float* __restrict__ logit_part)          // [4][65536][8], p = cb
{
    __shared__ unsigned short smem[24576];       // 49152 B; loop dbuf; epi: lh[128][136]
    float* fA = (float*)&smem[0];                // 2 buffers: f32 idx 0 / 4096 (128x32 f32 each)
    unsigned short* bB = &smem[16384];           // 2 buffers: u16 idx 0 / 4096 (128x32 bf16 each)

    int bid = blockIdx.x;                         // 2048 = 512 mb * 4 cb
    int mb = (bid >> 5) * 8 + (bid & 7);          // XCD-swizzled
    int cb = (bid >> 3) & 3;
    int m0 = mb * 128, n0 = cb * 128;

    int t = threadIdx.x;
    int wid = t >> 6, lane = t & 63;
    int wr = wid >> 1, wc = wid & 1;
    int l15 = lane & 15, l4 = lane >> 4;

    // A staging: thread t covers rows (t>>3)+j*32, 16B (4 f32) at swizzled slot
    int arow = t >> 3;
    int aswz = ((t & 7) ^ (arow & 7)) * 4;        // f32 elems; involution with read side
    const float* srcA = x + (size_t)(m0 + arow) * DD + aswz;
    int adst = arow * 32 + aswz;                  // f32 index into A buffer
    // B staging: r8-linear
    const unsigned short* srcB0 = WrTh + (size_t)(n0 + (t >> 2)) * DD + (t & 3) * 8;
    const unsigned short* srcB1 = srcB0 + (size_t)64 * DD;

    f32x4 acc[4][4];
    #pragma unroll
    for (int m = 0; m < 4; m++)
        #pragma unroll
        for (int n = 0; n < 4; n++) acc[m][n] = (f32x4){0.f, 0.f, 0.f, 0.f};

    // prologue: stage tile 0 into buffer 0
    #pragma unroll
    for (int j = 0; j < 4; j++)
        gload_lds16(srcA + (size_t)j * 32 * DD, fA + adst + j * 1024);
    gload_lds16(srcB0, bB + t * 8);
    gload_lds16(srcB1, bB + 2048 + t * 8);
    __syncthreads();

    for (int it = 0; it < 16; ++it) {
        int cur = it & 1;
        int ao = cur * 4096;                      // f32 elems
        int bo = cur * 4096;                      // u16 elems
        if (it < 15) {                            // stage next tile into other buffer
            int k0n = (it + 1) * 32;
            int aon = (cur ^ 1) * 4096, bon = (cur ^ 1) * 4096;
            #pragma unroll
            for (int j = 0; j < 4; j++)
                gload_lds16(srcA + (size_t)j * 32 * DD + k0n, fA + aon + adst + j * 1024);
            gload_lds16(srcB0 + k0n, bB + bon + t * 8);
            gload_lds16(srcB1 + k0n, bB + bon + 2048 + t * 8);
        }
        // A fragments: f32 swizzled reads + cvt
        bf16x8 fa[4], fb[4];
        #pragma unroll
        for (int m = 0; m < 4; m++) {
            int r = wr * 64 + m * 16 + l15;
            int s0 = (l4 * 2) ^ (r & 7), s1 = (l4 * 2 + 1) ^ (r & 7);
            f32x4 lo = *(const f32x4*)&fA[ao + r * 32 + s0 * 4];
            f32x4 hi = *(const f32x4*)&fA[ao + r * 32 + s1 * 4];
            #pragma unroll
            for (int j = 0; j < 4; j++) { fa[m][j] = (__bf16)lo[j]; fa[m][4 + j] = (__bf16)hi[j]; }
        }
        #pragma unroll
        for (int n = 0; n < 4; n++)
            fb[n] = *(const bf16x8*)&bB[bo + (wc * 64 + n * 16 + l15) * 32 + l4 * 8];
        #pragma unroll
        for (int m = 0; m < 4; m++)
            #pragma unroll
            for (int n = 0; n < 4; n++)
                acc[m][n] = mfma_bf16(fa[m], fb[n], acc[m][n]);
        __syncthreads();                          // drains vmcnt: next buffer ready
    }

    // epilogue 1: bias + relu -> h tile (bf16) in smem as lh[128][136]
    float bcol[4];
    #pragma unroll
    for (int n = 0; n < 4; n++) bcol[n] = b_root[n0 + wc * 64 + n * 16 + l15];
    #pragma unroll
    for (int n = 0; n < 4; n++) {
        int coll = wc * 64 + n * 16 + l15;
        #pragma unroll
        for (int m = 0; m < 4; m++) {
            int rl = wr * 64 + m * 16 + l4 * 4;
            #pragma unroll
            for (int i = 0; i < 4; i++) {
                float v = acc[m][n][i] + bcol[n];
                v = v > 0.f ? v : 0.f;
                smem[(rl + i) * 136 + coll] = f2bf(v);
            }
        }
    }
    __syncthreads();

    // epilogue 2a: vectorized h store from lh
    {
        int r = t >> 1, c0s = (t & 1) * 64;
        unsigned short* dst = hbuf + (size_t)(m0 + r) * DD + n0 + c0s;
        #pragma unroll
        for (int j = 0; j < 8; j++)
            *(u16x8*)(dst + j * 8) = *(const u16x8*)&smem[r * 136 + c0s + j * 8];
    }

    // epilogue 2b: logit partial = lh_tile @ W_dec[n0:n0+128][:] via MFMA
    f32x4 acc2[2];
    acc2[0] = (f32x4){0.f, 0.f, 0.f, 0.f};
    acc2[1] = (f32x4){0.f, 0.f, 0.f, 0.f};
    #pragma unroll
    for (int kk = 0; kk < 4; kk++) {
        bf16x8 bb = *(const bf16x8*)(WdT + (size_t)l15 * DD + n0 + kk * 32 + l4 * 8);
        #pragma unroll
        for (int m2 = 0; m2 < 2; m2++) {
            bf16x8 aa = *(const bf16x8*)&smem[(wid * 32 + m2 * 16 + l15) * 136 + kk * 32 + l4 * 8];
            acc2[m2] = mfma_bf16(aa, bb, acc2[m2]);
        }
    }
    if (l15 < 8) {
        #pragma unroll
        for (int m2 = 0; m2 < 2; m2++)
            #pragma unroll
            for (int i = 0; i < 4; i++) {
                int rowg = m0 + wid * 32 + m2 * 16 + l4 * 4 + i;
                logit_part[((size_t)cb * 65536 + rowg) * 8 + l15] = acc2[m2][i];
            }
    }
}

// ---------- K2: dec = softmax(sum of 4 partials, f64 sum); route; gap-flag ----------
__global__ __launch_bounds__(256) void k_dec(
    const float* __restrict__ logit_part,
    const float* __restrict__ b_dec,
    float* __restrict__ out,
    int* __restrict__ route,
    int* __restrict__ meta,
    int* __restrict__ rescue_list)
{
    int b = blockIdx.x * 256 + threadIdx.x;
    double lg[8];
    #pragma unroll
    for (int o = 0; o < 8; o++) lg[o] = (double)b_dec[o];
    #pragma unroll
    for (int ppp = 0; ppp < 4; ppp++) {        // fixed order: deterministic
        #pragma unroll
        for (int o = 0; o < 8; o++)
            lg[o] += (double)logit_part[((size_t)ppp * 65536 + b) * 8 + o];
    }
    double mx = -1e300, mx2 = -1e300; int idx = 0;
    #pragma unroll
    for (int o = 0; o < 8; o++) {
        if (lg[o] > mx) { mx2 = mx; mx = lg[o]; idx = o; }
        else if (lg[o] > mx2) mx2 = lg[o];
    }
    float ev[8], s = 0.f;
    #pragma unroll
    for (int o = 0; o < 8; o++) { ev[o] = expf((float)(lg[o] - mx)); s += ev[o]; }
    float inv = 1.f / s;
    float4 o0, o1;
    o0.x = ev[0]*inv; o0.y = ev[1]*inv; o0.z = ev[2]*inv; o0.w = ev[3]*inv;
    o1.x = ev[4]*inv; o1.y = ev[5]*inv; o1.z = ev[6]*inv; o1.w = ev[7]*inv;
    float4* op = (float4*)(out + (size_t)b * 16);
    op[0] = o0; op[1] = o1;
    route[b] = idx;
    if (mx - mx2 < 3e-3) {                     // near-tie (~8 sigma of bf16-GEMM logit err)
        int pos = atomicAdd(&meta[27], 1);
        if (pos < 8192) rescue_list[pos] = b;
    }
}

// ---------- K2b: exact f64 rescue (dec + route) ----------
__global__ __launch_bounds__(256) void k_rescue(
    const float* __restrict__ x,
    const float* __restrict__ W_root,
    const float* __restrict__ b_root,
    const float* __restrict__ W_dec,
    const float* __restrict__ b_dec,
    const int* __restrict__ rescue_list,
    const int* __restrict__ meta,
    float* __restrict__ out,
    int* __restrict__ route)
{
    int nresc = min(meta[27], 8192);
    if ((int)blockIdx.x >= nresc) return;
    int row = rescue_list[blockIdx.x];
    int t = threadIdx.x;

    __shared__ float xr[512];
    __shared__ double red[4][8];
    xr[t * 2]     = x[(size_t)row * DD + t * 2];
    xr[t * 2 + 1] = x[(size_t)row * DD + t * 2 + 1];
    __syncthreads();

    int d0 = t, d1 = t + 256;
    double a0 = 0.0, a1 = 0.0;
    for (int k = 0; k < DD; k++) {
        double xv = (double)xr[k];
        a0 += xv * (double)W_root[(size_t)k * DD + d0];
        a1 += xv * (double)W_root[(size_t)k * DD + d1];
    }
    double h0 = fmax(a0 + (double)b_root[d0], 0.0);
    double h1 = fmax(a1 + (double)b_root[d1], 0.0);
    double so[8];
    #pragma unroll
    for (int o = 0; o < 8; o++)
        so[o] = h0 * (double)W_dec[d0 * 8 + o] + h1 * (double)W_dec[d1 * 8 + o];
    #pragma unroll
    for (int d = 1; d < 64; d <<= 1)
        #pragma unroll
        for (int o = 0; o < 8; o++) so[o] += __shfl_xor(so[o], d, 64);
    if ((t & 63) == 0) {
        #pragma unroll
        for (int o = 0; o < 8; o++) red[t >> 6][o] = so[o];
    }
    __syncthreads();
    if (t == 0) {
        double lg[8]; double mx = -1e300; int idx = 0;
        #pragma unroll
        for (int o = 0; o < 8; o++) {
            lg[o] = red[0][o] + red[1][o] + red[2][o] + red[3][o] + (double)b_dec[o];
            if (lg[o] > mx) { mx = lg[o]; idx = o; }
        }
        double ev[8], s = 0.0;
        #pragma unroll
        for (int o = 0; o < 8; o++) { ev[o] = exp(lg[o] - mx); s += ev[o]; }
        double inv = 1.0 / s;
        float4 o0, o1;
        o0.x = (float)(ev[0]*inv); o0.y = (float)(ev[1]*inv);
        o0.z = (float)(ev[2]*inv); o0.w = (float)(ev[3]*inv);
        o1.x = (float)(ev[4]*inv); o1.y = (float)(ev[5]*inv);
        o1.z = (float)(ev[6]*inv); o1.w = (float)(ev[7]*inv);
        float4* op = (float4*)(out + (size_t)row * 16);
        op[0] = o0; op[1] = o1;
        route[row] = idx;
    }
}

// ---------- K2c: count routes — ballot-aggregated, 8 atomics/block ----------
__global__ __launch_bounds__(256) void k_count(
    const int* __restrict__ route, int* __restrict__ meta)
{
    __shared__ int wcnt[4][8];
    int b = blockIdx.x * 256 + threadIdx.x;
    int e = route[b];
    int lane = threadIdx.x & 63, wv = threadIdx.x >> 6;
    #pragma unroll
    for (int ex = 0; ex < 8; ex++) {
        unsigned long long m = __ballot(e == ex);
        if (lane == 0) wcnt[wv][ex] = __popcll(m);
    }
    __syncthreads();
    if (threadIdx.x < 8) {
        int ex = threadIdx.x;
        atomicAdd(&meta[ex], wcnt[0][ex] + wcnt[1][ex] + wcnt[2][ex] + wcnt[3][ex]);
    }
}

// ---------- K3: scan ----------
__global__ void k_scan(int* __restrict__ meta)
{
    if (threadIdx.x == 0 && blockIdx.x == 0) {
        int run = 0, rb = 0;
        for (int e = 0; e < 8; e++) {
            int c = meta[e];
            meta[16 + e] = run;
            meta[8 + e]  = run;
            int n = (c + 127) >> 7;
            for (int j = 0; j < n; j++) meta[32 + rb + j] = e | (j << 8);
            rb += n;
            run += n << 7;
        }
        meta[24] = rb;
    }
}

// ---------- K4: scatter — ballot-ranked, 8 atomics/block ----------
__global__ __launch_bounds__(256) void k_scatter(
    const int* __restrict__ route, int* __restrict__ meta, int* __restrict__ rows_list)
{
    __shared__ int wcnt[4][8];
    __shared__ int wbase[4][8];
    int b = blockIdx.x * 256 + threadIdx.x;
    int e = route[b];
    int lane = threadIdx.x & 63, wv = threadIdx.x >> 6;
    unsigned long long mymask = 0;
    #pragma unroll
    for (int ex = 0; ex < 8; ex++) {
        unsigned long long m = __ballot(e == ex);
        if (e == ex) mymask = m;
        if (lane == 0) wcnt[wv][ex] = __popcll(m);
    }
    int myrank = __popcll(mymask & ((1ULL << lane) - 1ULL));
    __syncthreads();
    if (threadIdx.x < 8) {
        int ex = threadIdx.x;
        int c0 = wcnt[0][ex], c1 = wcnt[1][ex], c2 = wcnt[2][ex], c3 = wcnt[3][ex];
        int base = atomicAdd(&meta[8 + ex], c0 + c1 + c2 + c3);
        wbase[0][ex] = base;
        wbase[1][ex] = base + c0;
        wbase[2][ex] = base + c0 + c1;
        wbase[3][ex] = base + c0 + c1 + c2;
    }
    __syncthreads();
    rows_list[wbase[wv][e] + myrank] = b;
}

// ---------- K5: grouped leaf GEMM; double-buffered single-barrier K-loop ----------
__global__ __launch_bounds__(256) void k_gemm2(
    const unsigned short* __restrict__ hbuf,
    const unsigned short* __restrict__ WlT,
    const float* __restrict__ b_leaf,
    const unsigned short* __restrict__ WldT,
    const int* __restrict__ rows_list,
    const int* __restrict__ meta,
    float* __restrict__ ldec_part)           // [4][65536][8]
{
    __shared__ unsigned short smem[17408];       // 34816 B; loop dbuf; epi: lh[128][136]
    // A buffers: u16 idx 0 / 4096;  B buffers: u16 idx 8192 / 12288 (128x32 bf16 each)

    int bid = blockIdx.x;
    int rbid = (bid >> 5) * 8 + (bid & 7);
    int cb = (bid >> 3) & 3;
    if (rbid >= meta[24]) return;
    int pk = meta[32 + rbid];
    int e = pk & 255, lrb = pk >> 8;
    int poff_e = meta[16 + e], cnt_e = meta[e];
    int n0 = cb * 128;

    int t = threadIdx.x;
    int wid = t >> 6, lane = t & 63;
    int wr = wid >> 1, wc = wid & 1;
    int l15 = lane & 15, l4 = lane >> 4;

    int slot0 = poff_e + lrb * 128 + (t >> 2);
    int slot1 = slot0 + 64;
    int lastv = poff_e + cnt_e - 1;
    int grow0 = rows_list[min(slot0, lastv)];    // clamp pad slots (idempotent recompute)
    int grow1 = rows_list[min(slot1, lastv)];
    const unsigned short* srcA0 = hbuf + (size_t)grow0 * DD + (t & 3) * 8;
    const unsigned short* srcA1 = hbuf + (size_t)grow1 * DD + (t & 3) * 8;
    const unsigned short* srcB0 = WlT + (size_t)e * DD * DD + (size_t)(n0 + (t >> 2)) * DD + (t & 3) * 8;
    const unsigned short* srcB1 = srcB0 + (size_t)64 * DD;

    f32x4 acc[4][4];
    #pragma unroll
    for (int m = 0; m < 4; m++)
        #pragma unroll
        for (int n = 0; n < 4; n++) acc[m][n] = (f32x4){0.f, 0.f, 0.f, 0.f};

    // prologue: stage tile 0 into buffer 0
    gload_lds16(srcA0, &smem[t * 8]);
    gload_lds16(srcA1, &smem[2048 + t * 8]);
    gload_lds16(srcB0, &smem[8192 + t * 8]);
    gload_lds16(srcB1, &smem[8192 + 2048 + t * 8]);
    __syncthreads();

    for (int it = 0; it < 16; ++it) {
        int cur = it & 1;
        int ao = cur * 4096, bo = 8192 + cur * 4096;
        if (it < 15) {
            int k0n = (it + 1) * 32;
            int aon = (cur ^ 1) * 4096, bon = 8192 + (cur ^ 1) * 4096;
            gload_lds16(srcA0 + k0n, &smem[aon + t * 8]);
            gload_lds16(srcA1 + k0n, &smem[aon + 2048 + t * 8]);
            gload_lds16(srcB0 + k0n, &smem[bon + t * 8]);
            gload_lds16(srcB1 + k0n, &smem[bon + 2048 + t * 8]);
        }
        bf16x8 af[4], bfr[4];
        #pragma unroll
        for (int m = 0; m < 4; m++)
            af[m] = *(const bf16x8*)&smem[ao + (wr * 64 + m * 16 + l15) * 32 + l4 * 8];
        #pragma unroll
        for (int n = 0; n < 4; n++)
            bfr[n] = *(const bf16x8*)&smem[bo + (wc * 64 + n * 16 + l15) * 32 + l4 * 8];
        #pragma unroll
        for (int m = 0; m < 4; m++)
            #pragma unroll
            for (int n = 0; n < 4; n++)
                acc[m][n] = mfma_bf16(af[m], bfr[n], acc[m][n]);
        __syncthreads();
    }

    // epilogue 1: bias + relu -> lh tile (bf16) in smem
    float bcol[4];
    #pragma unroll
    for (int n = 0; n < 4; n++) bcol[n] = b_leaf[(size_t)e * DD + n0 + wc * 64 + n * 16 + l15];
    #pragma unroll
    for (int n = 0; n < 4; n++) {
        int coll = wc * 64 + n * 16 + l15;
        #pragma unroll
        for (int m = 0; m < 4; m++) {
            int rl = wr * 64 + m * 16 + l4 * 4;
            #pragma unroll
            for (int i = 0; i < 4; i++) {
                float v = acc[m][n][i] + bcol[n];
                v = v > 0.f ? v : 0.f;
                smem[(rl + i) * 136 + coll] = f2bf(v);
            }
        }
    }
    __syncthreads();

    // epilogue 2: ldec partial = lh_tile @ W_ldec[e][n0:n0+128][:] via MFMA
    f32x4 acc2[2];
    acc2[0] = (f32x4){0.f, 0.f, 0.f, 0.f};
    acc2[1] = (f32x4){0.f, 0.f, 0.f, 0.f};
    #pragma unroll
    for (int kk = 0; kk < 4; kk++) {
        bf16x8 bb = *(const bf16x8*)(WldT + ((size_t)e * 16 + l15) * DD + n0 + kk * 32 + l4 * 8);
        #pragma unroll
        for (int m2 = 0; m2 < 2; m2++) {
            bf16x8 aa = *(const bf16x8*)&smem[(wid * 32 + m2 * 16 + l15) * 136 + kk * 32 + l4 * 8];
            acc2[m2] = mfma_bf16(aa, bb, acc2[m2]);
        }
    }
    if (l15 < 8) {
        #pragma unroll
        for (int m2 = 0; m2 < 2; m2++)
            #pragma unroll
            for (int i = 0; i < 4; i++) {
                int rl = wid * 32 + m2 * 16 + l4 * 4 + i;
                int s = min(poff_e + lrb * 128 + rl, lastv);
                int brow = rows_list[s];             // pad slots: duplicate identical writes
                ldec_part[((size_t)cb * 65536 + brow) * 8 + l15] = acc2[m2][i];
            }
    }
}

// ---------- K6: sel softmax ----------
__global__ __launch_bounds__(256) void k_sel(
    const float* __restrict__ ldec_part,
    const int* __restrict__ route,
    const float* __restrict__ b_ldec,
    float* __restrict__ out)
{
    int b = blockIdx.x * 256 + threadIdx.x;
    int e = route[b];
    float lg[8];
    #pragma unroll
    for (int o = 0; o < 8; o++) lg[o] = b_ldec[e * 8 + o];
    #pragma unroll
    for (int p = 0; p < 4; p++) {
        const float4* ap = (const float4*)(ldec_part + ((size_t)p * 65536 + b) * 8);
        float4 a0 = ap[0], a1 = ap[1];
        lg[0]+=a0.x; lg[1]+=a0.y; lg[2]+=a0.z; lg[3]+=a0.w;
        lg[4]+=a1.x; lg[5]+=a1.y; lg[6]+=a1.z; lg[7]+=a1.w;
    }
    float mx = -1e30f;
    #pragma unroll
    for (int o = 0; o < 8; o++) mx = fmaxf(mx, lg[o]);
    float ev[8], s = 0.f;
    #pragma unroll
    for (int o = 0; o < 8; o++) { ev[o] = expf(lg[o] - mx); s += ev[o]; }
    float inv = 1.f / s;
    float4 o0, o1;
    o0.x = ev[0]*inv; o0.y = ev[1]*inv; o0.z = ev[2]*inv; o0.w = ev[3]*inv;
    o1.x = ev[4]*inv; o1.y = ev[5]*inv; o1.z = ev[6]*inv; o1.w = ev[7]*inv;
    float4* op = (float4*)(out + (size_t)b * 16 + 8);
    op[0] = o0; op[1] = o1;
}

extern "C" void kernel_launch(void* const* d_in, const int* in_sizes, int n_in,
                              void* d_out, int out_size, void* d_ws, size_t ws_size,
                              hipStream_t stream)
{
    const float* x      = (const float*)d_in[0];
    const float* W_root = (const float*)d_in[1];
    const float* b_root = (const float*)d_in[2];
    const float* W_dec  = (const float*)d_in[3];
    const float* b_dec  = (const float*)d_in[4];
    const float* W_leaf = (const float*)d_in[5];
    const float* b_leaf = (const float*)d_in[6];
    const float* W_ldec = (const float*)d_in[7];
    const float* b_ldec = (const float*)d_in[8];
    float* out = (float*)d_out;

    char* w = (char*)d_ws;
    unsigned short* hbuf       = (unsigned short*)(w);               // 67,108,864
    float*          logit_part = (float*)(w + 67108864);             //  8,388,608
    unsigned short* WlT        = (unsigned short*)(w + 75497472);    //  4,194,304
    unsigned short* WldT       = (unsigned short*)(w + 79691776);    //    131,072
    unsigned short* WdT        = (unsigned short*)(w + 79822848);    //     16,384
    float*          ldec_part  = (float*)(w + 79839232);             //  8,388,608
    int*            route      = (int*)(w + 88227840);               //    262,144
    int*            rows_list  = (int*)(w + 88489984);               //    266,240
    unsigned short* WrTh       = (unsigned short*)(w + 88756224);    //    524,288
    int*            rescue     = (int*)(w + 89280512);               //     32,768
    int*            meta       = (int*)(w + 89313280);               //      4,096
    const size_t WS_NEED = 89317376ULL;
    if (ws_size < WS_NEED) return;

    (void)hipMemsetAsync(meta, 0, 4096, stream);

    k_wtr    <<<64,   256, 0, stream>>>(W_root, WrTh);
    k_trW    <<<512,  256, 0, stream>>>(W_leaf, WlT);
    k_trpad  <<<256,  256, 0, stream>>>(W_ldec, WldT);
    k_trdec  <<<32,   256, 0, stream>>>(W_dec, WdT);
    k_root   <<<2048, 256, 0, stream>>>(x, WrTh, b_root, WdT, hbuf, logit_part);
    k_dec    <<<256,  256, 0, stream>>>(logit_part, b_dec, out, route, meta, rescue);
    k_rescue <<<8192, 256, 0, stream>>>(x, W_root, b_root, W_dec, b_dec, rescue, meta, out, route);
    k_count  <<<256,  256, 0, stream>>>(route, meta);
    k_scan   <<<1,    64,  0, stream>>>(meta);
    k_scatter<<<256,  256, 0, stream>>>(route, meta, rows_list);
    k_gemm2  <<<2080, 256, 0, stream>>>(hbuf, WlT, b_leaf, WldT, rows_list, meta, ldec_part);
    k_sel    <<<256,  256, 0, stream>>>(ldec_part, route, b_ldec, out);
}

// Round 14
// 262.189 us; speedup vs baseline: 1.1629x; 1.0167x over previous
//
#include <hip/hip_runtime.h>
#include <stdint.h>

#define DD   512
#define EE   8

typedef __bf16 bf16x8 __attribute__((ext_vector_type(8)));
typedef float  f32x4  __attribute__((ext_vector_type(4)));
typedef unsigned short u16x8 __attribute__((ext_vector_type(8)));

__device__ __forceinline__ unsigned short f2bf(float f) {  // RTNE
    union { float f; unsigned int i; } v; v.f = f;
    unsigned int x = v.i;
    x += 0x7fffu + ((x >> 16) & 1u);
    return (unsigned short)(x >> 16);
}
__device__ __forceinline__ void gload_lds16(const void* g, void* l) {
    __builtin_amdgcn_global_load_lds(
        (const __attribute__((address_space(1))) unsigned int*)g,
        (__attribute__((address_space(3))) unsigned int*)l, 16, 0, 0);
}
__device__ __forceinline__ f32x4 mfma_bf16(bf16x8 a, bf16x8 b, f32x4 c) {
    return __builtin_amdgcn_mfma_f32_16x16x32_bf16(a, b, c, 0, 0, 0);
}

// ---------- K0r: W_root (f32) [k][n] -> WrTh (bf16) [n][k] ----------
__global__ __launch_bounds__(256) void k_wtr(
    const float* __restrict__ W_root, unsigned short* __restrict__ WrTh)
{
    __shared__ unsigned short tile[64][65];
    int tl = blockIdx.x, tr = tl >> 3, tc = tl & 7;   // 64 tiles
    int t = threadIdx.x;
    #pragma unroll
    for (int j = 0; j < 16; j++) {
        int i2 = t + j * 256; int r = i2 >> 6, c = i2 & 63;
        tile[r][c] = f2bf(W_root[(size_t)(tr * 64 + r) * DD + tc * 64 + c]);
    }
    __syncthreads();
    #pragma unroll
    for (int j = 0; j < 16; j++) {
        int i2 = t + j * 256; int r = i2 >> 6, c = i2 & 63;
        WrTh[(size_t)(tc * 64 + r) * DD + tr * 64 + c] = tile[c][r];
    }
}

// ---------- K0a: W_leaf (f32) [e][d][h] -> WlT (bf16) [e][h][d] ----------
__global__ __launch_bounds__(256) void k_trW(
    const float* __restrict__ W_leaf, unsigned short* __restrict__ WlT)
{
    __shared__ unsigned short tile[64][65];
    int bid = blockIdx.x;            // 8 mats * 64 tiles
    int e = bid >> 6;
    int tl = bid & 63, tr = tl >> 3, tc = tl & 7;
    const float* src = W_leaf + (size_t)e * DD * DD;
    unsigned short* dst = WlT + (size_t)e * DD * DD;
    int t = threadIdx.x;
    #pragma unroll
    for (int j = 0; j < 16; j++) {
        int i2 = t + j * 256; int r = i2 >> 6, c = i2 & 63;
        tile[r][c] = f2bf(src[(size_t)(tr * 64 + r) * DD + tc * 64 + c]);
    }
    __syncthreads();
    #pragma unroll
    for (int j = 0; j < 16; j++) {
        int i2 = t + j * 256; int r = i2 >> 6, c = i2 & 63;
        dst[(size_t)(tc * 64 + r) * DD + tr * 64 + c] = tile[c][r];
    }
}

// ---------- K0b: W_ldec (f32) [e][d][o] -> WldT (bf16) [e][16][512], zero-padded ----------
__global__ __launch_bounds__(256) void k_trpad(
    const float* __restrict__ W_ldec, unsigned short* __restrict__ WldT)
{
    int idx = blockIdx.x * 256 + threadIdx.x;      // 65536
    int e = idx >> 13, rem = idx & 8191;
    int o = rem >> 9, k = rem & 511;
    unsigned short v = 0;
    if (o < 8) v = f2bf(W_ldec[((size_t)e * DD + k) * EE + o]);
    WldT[idx] = v;
}

// ---------- K0c: W_dec (f32) [d][o] -> WdT (bf16) [16][512], zero-padded ----------
__global__ __launch_bounds__(256) void k_trdec(
    const float* __restrict__ W_dec, unsigned short* __restrict__ WdT)
{
    int idx = blockIdx.x * 256 + threadIdx.x;      // 8192
    int o = idx >> 9, k = idx & 511;
    WdT[idx] = (o < 8) ? f2bf(W_dec[(size_t)k * EE + o]) : (unsigned short)0;
}

// ---------- K1: bf16 MFMA root GEMM; dbuf K-loop with T14 async-stage split ----------
// A: reg-staged (issue f32 loads EARLY, cvt+ds_write LATE, after MFMA phase).
// B: global_load_lds direct into alternate buffer. One __syncthreads per K-step.
__global__ __launch_bounds__(256) void k_root(
    const float* __restrict__ x,
    const unsigned short* __restrict__ WrTh,
    const float* __restrict__ b_root,
    const unsigned short* __restrict__ WdT,
    unsigned short* __restrict__ hbuf,
    float* __restrict__ logit_part)          // [4][65536][8], p = cb
{
    __shared__ unsigned short smem[17408];       // 34816 B; dbuf A@0/4096, B@8192/12288; epi lh[128][136]

    int bid = blockIdx.x;                         // 2048 = 512 mb * 4 cb
    int mb = (bid >> 5) * 8 + (bid & 7);          // XCD-swizzled
    int cb = (bid >> 3) & 3;
    int m0 = mb * 128, n0 = cb * 128;

    int t = threadIdx.x;
    int wid = t >> 6, lane = t & 63;
    int wr = wid >> 1, wc = wid & 1;
    int l15 = lane & 15, l4 = lane >> 4;

    // A: reg-staged f32 -> bf16 (row t>>1, 16 k at (t&1)*16)
    int ar = t >> 1, ah16 = (t & 1) * 16;
    const float* pA = x + (size_t)(m0 + ar) * DD + ah16;
    // B: global_load_lds direct (r8-linear)
    const unsigned short* srcB0 = WrTh + (size_t)(n0 + (t >> 2)) * DD + (t & 3) * 8;
    const unsigned short* srcB1 = srcB0 + (size_t)64 * DD;

    f32x4 acc[4][4];
    #pragma unroll
    for (int m = 0; m < 4; m++)
        #pragma unroll
        for (int n = 0; n < 4; n++) acc[m][n] = (f32x4){0.f, 0.f, 0.f, 0.f};

    // prologue: stage tile 0 into buffer 0
    {
        const float4* p = (const float4*)pA;
        float4 c0 = p[0], c1 = p[1], c2 = p[2], c3 = p[3];
        float vv[16] = {c0.x,c0.y,c0.z,c0.w, c1.x,c1.y,c1.z,c1.w,
                        c2.x,c2.y,c2.z,c2.w, c3.x,c3.y,c3.z,c3.w};
        bf16x8 hv0, hv1;
        #pragma unroll
        for (int j = 0; j < 8; j++) { hv0[j] = (__bf16)vv[j]; hv1[j] = (__bf16)vv[8 + j]; }
        *(bf16x8*)&smem[ar * 32 + ah16]     = hv0;
        *(bf16x8*)&smem[ar * 32 + ah16 + 8] = hv1;
        gload_lds16(srcB0, &smem[8192 + t * 8]);
        gload_lds16(srcB1, &smem[8192 + 2048 + t * 8]);
    }
    __syncthreads();

    for (int it = 0; it < 16; ++it) {
        int cur = it & 1;
        int ao = cur * 4096, bo = 8192 + cur * 4096;
        int aon = (cur ^ 1) * 4096, bon = 8192 + (cur ^ 1) * 4096;

        // (1) issue next tile's loads EARLY: A f32 -> regs, B -> LDS (async)
        float4 n0v, n1v, n2v, n3v;
        if (it < 15) {
            int k0n = (it + 1) * 32;
            const float4* p = (const float4*)(pA + k0n);
            n0v = p[0]; n1v = p[1]; n2v = p[2]; n3v = p[3];
            gload_lds16(srcB0 + k0n, &smem[bon + t * 8]);
            gload_lds16(srcB1 + k0n, &smem[bon + 2048 + t * 8]);
        }

        // (2) compute current tile — pure bf16 ds_read + MFMA (loads fly underneath)
        bf16x8 fa[4], fb[4];
        #pragma unroll
        for (int m = 0; m < 4; m++)
            fa[m] = *(const bf16x8*)&smem[ao + (wr * 64 + m * 16 + l15) * 32 + l4 * 8];
        #pragma unroll
        for (int n = 0; n < 4; n++)
            fb[n] = *(const bf16x8*)&smem[bo + (wc * 64 + n * 16 + l15) * 32 + l4 * 8];
        #pragma unroll
        for (int m = 0; m < 4; m++)
            #pragma unroll
            for (int n = 0; n < 4; n++)
                acc[m][n] = mfma_bf16(fa[m], fb[n], acc[m][n]);

        // (3) cvt A-regs and write into other buffer LATE
        if (it < 15) {
            float vv[16] = {n0v.x,n0v.y,n0v.z,n0v.w, n1v.x,n1v.y,n1v.z,n1v.w,
                            n2v.x,n2v.y,n2v.z,n2v.w, n3v.x,n3v.y,n3v.z,n3v.w};
            bf16x8 hv0, hv1;
            #pragma unroll
            for (int j = 0; j < 8; j++) { hv0[j] = (__bf16)vv[j]; hv1[j] = (__bf16)vv[8 + j]; }
            *(bf16x8*)&smem[aon + ar * 32 + ah16]     = hv0;
            *(bf16x8*)&smem[aon + ar * 32 + ah16 + 8] = hv1;
        }
        __syncthreads();                          // drains B gloads + A ds_writes
    }

    // epilogue 1: bias + relu -> h tile (bf16) in smem as lh[128][136]
    float bcol[4];
    #pragma unroll
    for (int n = 0; n < 4; n++) bcol[n] = b_root[n0 + wc * 64 + n * 16 + l15];
    #pragma unroll
    for (int n = 0; n < 4; n++) {
        int coll = wc * 64 + n * 16 + l15;
        #pragma unroll
        for (int m = 0; m < 4; m++) {
            int rl = wr * 64 + m * 16 + l4 * 4;
            #pragma unroll
            for (int i = 0; i < 4; i++) {
                float v = acc[m][n][i] + bcol[n];
                v = v > 0.f ? v : 0.f;
                smem[(rl + i) * 136 + coll] = f2bf(v);
            }
        }
    }
    __syncthreads();

    // epilogue 2a: vectorized h store from lh
    {
        int r = t >> 1, c0s = (t & 1) * 64;
        unsigned short* dst = hbuf + (size_t)(m0 + r) * DD + n0 + c0s;
        #pragma unroll
        for (int j = 0; j < 8; j++)
            *(u16x8*)(dst + j * 8) = *(const u16x8*)&smem[r * 136 + c0s + j * 8];
    }

    // epilogue 2b: logit partial = lh_tile @ W_dec[n0:n0+128][:] via MFMA
    f32x4 acc2[2];
    acc2[0] = (f32x4){0.f, 0.f, 0.f, 0.f};
    acc2[1] = (f32x4){0.f, 0.f, 0.f, 0.f};
    #pragma unroll
    for (int kk = 0; kk < 4; kk++) {
        bf16x8 bb = *(const bf16x8*)(WdT + (size_t)l15 * DD + n0 + kk * 32 + l4 * 8);
        #pragma unroll
        for (int m2 = 0; m2 < 2; m2++) {
            bf16x8 aa = *(const bf16x8*)&smem[(wid * 32 + m2 * 16 + l15) * 136 + kk * 32 + l4 * 8];
            acc2[m2] = mfma_bf16(aa, bb, acc2[m2]);
        }
    }
    if (l15 < 8) {
        #pragma unroll
        for (int m2 = 0; m2 < 2; m2++)
            #pragma unroll
            for (int i = 0; i < 4; i++) {
                int rowg = m0 + wid * 32 + m2 * 16 + l4 * 4 + i;
                logit_part[((size_t)cb * 65536 + rowg) * 8 + l15] = acc2[m2][i];
            }
    }
}

// ---------- K2: dec = softmax(sum of 4 partials, f64 sum); route; gap-flag ----------
__global__ __launch_bounds__(256) void k_dec(
    const float* __restrict__ logit_part,
    const float* __restrict__ b_dec,
    float* __restrict__ out,
    int* __restrict__ route,
    int* __restrict__ meta,
    int* __restrict__ rescue_list)
{
    int b = blockIdx.x * 256 + threadIdx.x;
    double lg[8];
    #pragma unroll
    for (int o = 0; o < 8; o++) lg[o] = (double)b_dec[o];
    #pragma unroll
    for (int ppp = 0; ppp < 4; ppp++) {        // fixed order: deterministic
        #pragma unroll
        for (int o = 0; o < 8; o++)
            lg[o] += (double)logit_part[((size_t)ppp * 65536 + b) * 8 + o];
    }
    double mx = -1e300, mx2 = -1e300; int idx = 0;
    #pragma unroll
    for (int o = 0; o < 8; o++) {
        if (lg[o] > mx) { mx2 = mx; mx = lg[o]; idx = o; }
        else if (lg[o] > mx2) mx2 = lg[o];
    }
    float ev[8], s = 0.f;
    #pragma unroll
    for (int o = 0; o < 8; o++) { ev[o] = expf((float)(lg[o] - mx)); s += ev[o]; }
    float inv = 1.f / s;
    float4 o0, o1;
    o0.x = ev[0]*inv; o0.y = ev[1]*inv; o0.z = ev[2]*inv; o0.w = ev[3]*inv;
    o1.x = ev[4]*inv; o1.y = ev[5]*inv; o1.z = ev[6]*inv; o1.w = ev[7]*inv;
    float4* op = (float4*)(out + (size_t)b * 16);
    op[0] = o0; op[1] = o1;
    route[b] = idx;
    if (mx - mx2 < 3e-3) {                     // near-tie (~8 sigma of bf16-GEMM logit err)
        int pos = atomicAdd(&meta[27], 1);
        if (pos < 8192) rescue_list[pos] = b;
    }
}

// ---------- K2b: exact f64 rescue (dec + route) ----------
__global__ __launch_bounds__(256) void k_rescue(
    const float* __restrict__ x,
    const float* __restrict__ W_root,
    const float* __restrict__ b_root,
    const float* __restrict__ W_dec,
    const float* __restrict__ b_dec,
    const int* __restrict__ rescue_list,
    const int* __restrict__ meta,
    float* __restrict__ out,
    int* __restrict__ route)
{
    int nresc = min(meta[27], 8192);
    if ((int)blockIdx.x >= nresc) return;
    int row = rescue_list[blockIdx.x];
    int t = threadIdx.x;

    __shared__ float xr[512];
    __shared__ double red[4][8];
    xr[t * 2]     = x[(size_t)row * DD + t * 2];
    xr[t * 2 + 1] = x[(size_t)row * DD + t * 2 + 1];
    __syncthreads();

    int d0 = t, d1 = t + 256;
    double a0 = 0.0, a1 = 0.0;
    for (int k = 0; k < DD; k++) {
        double xv = (double)xr[k];
        a0 += xv * (double)W_root[(size_t)k * DD + d0];
        a1 += xv * (double)W_root[(size_t)k * DD + d1];
    }
    double h0 = fmax(a0 + (double)b_root[d0], 0.0);
    double h1 = fmax(a1 + (double)b_root[d1], 0.0);
    double so[8];
    #pragma unroll
    for (int o = 0; o < 8; o++)
        so[o] = h0 * (double)W_dec[d0 * 8 + o] + h1 * (double)W_dec[d1 * 8 + o];
    #pragma unroll
    for (int d = 1; d < 64; d <<= 1)
        #pragma unroll
        for (int o = 0; o < 8; o++) so[o] += __shfl_xor(so[o], d, 64);
    if ((t & 63) == 0) {
        #pragma unroll
        for (int o = 0; o < 8; o++) red[t >> 6][o] = so[o];
    }
    __syncthreads();
    if (t == 0) {
        double lg[8]; double mx = -1e300; int idx = 0;
        #pragma unroll
        for (int o = 0; o < 8; o++) {
            lg[o] = red[0][o] + red[1][o] + red[2][o] + red[3][o] + (double)b_dec[o];
            if (lg[o] > mx) { mx = lg[o]; idx = o; }
        }
        double ev[8], s = 0.0;
        #pragma unroll
        for (int o = 0; o < 8; o++) { ev[o] = exp(lg[o] - mx); s += ev[o]; }
        double inv = 1.0 / s;
        float4 o0, o1;
        o0.x = (float)(ev[0]*inv); o0.y = (float)(ev[1]*inv);
        o0.z = (float)(ev[2]*inv); o0.w = (float)(ev[3]*inv);
        o1.x = (float)(ev[4]*inv); o1.y = (float)(ev[5]*inv);
        o1.z = (float)(ev[6]*inv); o1.w = (float)(ev[7]*inv);
        float4* op = (float4*)(out + (size_t)row * 16);
        op[0] = o0; op[1] = o1;
        route[row] = idx;
    }
}

// ---------- K2c: count routes — ballot-aggregated, 8 atomics/block ----------
__global__ __launch_bounds__(256) void k_count(
    const int* __restrict__ route, int* __restrict__ meta)
{
    __shared__ int wcnt[4][8];
    int b = blockIdx.x * 256 + threadIdx.x;
    int e = route[b];
    int lane = threadIdx.x & 63, wv = threadIdx.x >> 6;
    #pragma unroll
    for (int ex = 0; ex < 8; ex++) {
        unsigned long long m = __ballot(e == ex);
        if (lane == 0) wcnt[wv][ex] = __popcll(m);
    }
    __syncthreads();
    if (threadIdx.x < 8) {
        int ex = threadIdx.x;
        atomicAdd(&meta[ex], wcnt[0][ex] + wcnt[1][ex] + wcnt[2][ex] + wcnt[3][ex]);
    }
}

// ---------- K3: scan ----------
__global__ void k_scan(int* __restrict__ meta)
{
    if (threadIdx.x == 0 && blockIdx.x == 0) {
        int run = 0, rb = 0;
        for (int e = 0; e < 8; e++) {
            int c = meta[e];
            meta[16 + e] = run;
            meta[8 + e]  = run;
            int n = (c + 127) >> 7;
            for (int j = 0; j < n; j++) meta[32 + rb + j] = e | (j << 8);
            rb += n;
            run += n << 7;
        }
        meta[24] = rb;
    }
}

// ---------- K4: scatter — ballot-ranked, 8 atomics/block ----------
__global__ __launch_bounds__(256) void k_scatter(
    const int* __restrict__ route, int* __restrict__ meta, int* __restrict__ rows_list)
{
    __shared__ int wcnt[4][8];
    __shared__ int wbase[4][8];
    int b = blockIdx.x * 256 + threadIdx.x;
    int e = route[b];
    int lane = threadIdx.x & 63, wv = threadIdx.x >> 6;
    unsigned long long mymask = 0;
    #pragma unroll
    for (int ex = 0; ex < 8; ex++) {
        unsigned long long m = __ballot(e == ex);
        if (e == ex) mymask = m;
        if (lane == 0) wcnt[wv][ex] = __popcll(m);
    }
    int myrank = __popcll(mymask & ((1ULL << lane) - 1ULL));
    __syncthreads();
    if (threadIdx.x < 8) {
        int ex = threadIdx.x;
        int c0 = wcnt[0][ex], c1 = wcnt[1][ex], c2 = wcnt[2][ex], c3 = wcnt[3][ex];
        int base = atomicAdd(&meta[8 + ex], c0 + c1 + c2 + c3);
        wbase[0][ex] = base;
        wbase[1][ex] = base + c0;
        wbase[2][ex] = base + c0 + c1;
        wbase[3][ex] = base + c0 + c1 + c2;
    }
    __syncthreads();
    rows_list[wbase[wv][e] + myrank] = b;
}

// ---------- K5: grouped leaf GEMM; double-buffered single-barrier K-loop ----------
__global__ __launch_bounds__(256) void k_gemm2(
    const unsigned short* __restrict__ hbuf,
    const unsigned short* __restrict__ WlT,
    const float* __restrict__ b_leaf,
    const unsigned short* __restrict__ WldT,
    const int* __restrict__ rows_list,
    const int* __restrict__ meta,
    float* __restrict__ ldec_part)           // [4][65536][8]
{
    __shared__ unsigned short smem[17408];       // 34816 B; loop dbuf; epi: lh[128][136]
    // A buffers: u16 idx 0 / 4096;  B buffers: u16 idx 8192 / 12288 (128x32 bf16 each)

    int bid = blockIdx.x;
    int rbid = (bid >> 5) * 8 + (bid & 7);
    int cb = (bid >> 3) & 3;
    if (rbid >= meta[24]) return;
    int pk = meta[32 + rbid];
    int e = pk & 255, lrb = pk >> 8;
    int poff_e = meta[16 + e], cnt_e = meta[e];
    int n0 = cb * 128;

    int t = threadIdx.x;
    int wid = t >> 6, lane = t & 63;
    int wr = wid >> 1, wc = wid & 1;
    int l15 = lane & 15, l4 = lane >> 4;

    int slot0 = poff_e + lrb * 128 + (t >> 2);
    int slot1 = slot0 + 64;
    int lastv = poff_e + cnt_e - 1;
    int grow0 = rows_list[min(slot0, lastv)];    // clamp pad slots (idempotent recompute)
    int grow1 = rows_list[min(slot1, lastv)];
    const unsigned short* srcA0 = hbuf + (size_t)grow0 * DD + (t & 3) * 8;
    const unsigned short* srcA1 = hbuf + (size_t)grow1 * DD + (t & 3) * 8;
    const unsigned short* srcB0 = WlT + (size_t)e * DD * DD + (size_t)(n0 + (t >> 2)) * DD + (t & 3) * 8;
    const unsigned short* srcB1 = srcB0 + (size_t)64 * DD;

    f32x4 acc[4][4];
    #pragma unroll
    for (int m = 0; m < 4; m++)
        #pragma unroll
        for (int n = 0; n < 4; n++) acc[m][n] = (f32x4){0.f, 0.f, 0.f, 0.f};

    // prologue: stage tile 0 into buffer 0
    gload_lds16(srcA0, &smem[t * 8]);
    gload_lds16(srcA1, &smem[2048 + t * 8]);
    gload_lds16(srcB0, &smem[8192 + t * 8]);
    gload_lds16(srcB1, &smem[8192 + 2048 + t * 8]);
    __syncthreads();

    for (int it = 0; it < 16; ++it) {
        int cur = it & 1;
        int ao = cur * 4096, bo = 8192 + cur * 4096;
        if (it < 15) {
            int k0n = (it + 1) * 32;
            int aon = (cur ^ 1) * 4096, bon = 8192 + (cur ^ 1) * 4096;
            gload_lds16(srcA0 + k0n, &smem[aon + t * 8]);
            gload_lds16(srcA1 + k0n, &smem[aon + 2048 + t * 8]);
            gload_lds16(srcB0 + k0n, &smem[bon + t * 8]);
            gload_lds16(srcB1 + k0n, &smem[bon + 2048 + t * 8]);
        }
        bf16x8 af[4], bfr[4];
        #pragma unroll
        for (int m = 0; m < 4; m++)
            af[m] = *(const bf16x8*)&smem[ao + (wr * 64 + m * 16 + l15) * 32 + l4 * 8];
        #pragma unroll
        for (int n = 0; n < 4; n++)
            bfr[n] = *(const bf16x8*)&smem[bo + (wc * 64 + n * 16 + l15) * 32 + l4 * 8];
        #pragma unroll
        for (int m = 0; m < 4; m++)
            #pragma unroll
            for (int n = 0; n < 4; n++)
                acc[m][n] = mfma_bf16(af[m], bfr[n], acc[m][n]);
        __syncthreads();
    }

    // epilogue 1: bias + relu -> lh tile (bf16) in smem
    float bcol[4];
    #pragma unroll
    for (int n = 0; n < 4; n++) bcol[n] = b_leaf[(size_t)e * DD + n0 + wc * 64 + n * 16 + l15];
    #pragma unroll
    for (int n = 0; n < 4; n++) {
        int coll = wc * 64 + n * 16 + l15;
        #pragma unroll
        for (int m = 0; m < 4; m++) {
            int rl = wr * 64 + m * 16 + l4 * 4;
            #pragma unroll
            for (int i = 0; i < 4; i++) {
                float v = acc[m][n][i] + bcol[n];
                v = v > 0.f ? v : 0.f;
                smem[(rl + i) * 136 + coll] = f2bf(v);
            }
        }
    }
    __syncthreads();

    // epilogue 2: ldec partial = lh_tile @ W_ldec[e][n0:n0+128][:] via MFMA
    f32x4 acc2[2];
    acc2[0] = (f32x4){0.f, 0.f, 0.f, 0.f};
    acc2[1] = (f32x4){0.f, 0.f, 0.f, 0.f};
    #pragma unroll
    for (int kk = 0; kk < 4; kk++) {
        bf16x8 bb = *(const bf16x8*)(WldT + ((size_t)e * 16 + l15) * DD + n0 + kk * 32 + l4 * 8);
        #pragma unroll
        for (int m2 = 0; m2 < 2; m2++) {
            bf16x8 aa = *(const bf16x8*)&smem[(wid * 32 + m2 * 16 + l15) * 136 + kk * 32 + l4 * 8];
            acc2[m2] = mfma_bf16(aa, bb, acc2[m2]);
        }
    }
    if (l15 < 8) {
        #pragma unroll
        for (int m2 = 0; m2 < 2; m2++)
            #pragma unroll
            for (int i = 0; i < 4; i++) {
                int rl = wid * 32 + m2 * 16 + l4 * 4 + i;
                int s = min(poff_e + lrb * 128 + rl, lastv);
                int brow = rows_list[s];             // pad slots: duplicate identical writes
                ldec_part[((size_t)cb * 65536 + brow) * 8 + l15] = acc2[m2][i];
            }
    }
}

// ---------- K6: sel softmax ----------
__global__ __launch_bounds__(256) void k_sel(
    const float* __restrict__ ldec_part,
    const int* __restrict__ route,
    const float* __restrict__ b_ldec,
    float* __restrict__ out)
{
    int b = blockIdx.x * 256 + threadIdx.x;
    int e = route[b];
    float lg[8];
    #pragma unroll
    for (int o = 0; o < 8; o++) lg[o] = b_ldec[e * 8 + o];
    #pragma unroll
    for (int p = 0; p < 4; p++) {
        const float4* ap = (const float4*)(ldec_part + ((size_t)p * 65536 + b) * 8);
        float4 a0 = ap[0], a1 = ap[1];
        lg[0]+=a0.x; lg[1]+=a0.y; lg[2]+=a0.z; lg[3]+=a0.w;
        lg[4]+=a1.x; lg[5]+=a1.y; lg[6]+=a1.z; lg[7]+=a1.w;
    }
    float mx = -1e30f;
    #pragma unroll
    for (int o = 0; o < 8; o++) mx = fmaxf(mx, lg[o]);
    float ev[8], s = 0.f;
    #pragma unroll
    for (int o = 0; o < 8; o++) { ev[o] = expf(lg[o] - mx); s += ev[o]; }
    float inv = 1.f / s;
    float4 o0, o1;
    o0.x = ev[0]*inv; o0.y = ev[1]*inv; o0.z = ev[2]*inv; o0.w = ev[3]*inv;
    o1.x = ev[4]*inv; o1.y = ev[5]*inv; o1.z = ev[6]*inv; o1.w = ev[7]*inv;
    float4* op = (float4*)(out + (size_t)b * 16 + 8);
    op[0] = o0; op[1] = o1;
}

extern "C" void kernel_launch(void* const* d_in, const int* in_sizes, int n_in,
                              void* d_out, int out_size, void* d_ws, size_t ws_size,
                              hipStream_t stream)
{
    const float* x      = (const float*)d_in[0];
    const float* W_root = (const float*)d_in[1];
    const float* b_root = (const float*)d_in[2];
    const float* W_dec  = (const float*)d_in[3];
    const float* b_dec  = (const float*)d_in[4];
    const float* W_leaf = (const float*)d_in[5];
    const float* b_leaf = (const float*)d_in[6];
    const float* W_ldec = (const float*)d_in[7];
    const float* b_ldec = (const float*)d_in[8];
    float* out = (float*)d_out;

    char* w = (char*)d_ws;
    unsigned short* hbuf       = (unsigned short*)(w);               // 67,108,864
    float*          logit_part = (float*)(w + 67108864);             //  8,388,608
    unsigned short* WlT        = (unsigned short*)(w + 75497472);    //  4,194,304
    unsigned short* WldT       = (unsigned short*)(w + 79691776);    //    131,072
    unsigned short* WdT        = (unsigned short*)(w + 79822848);    //     16,384
    float*          ldec_part  = (float*)(w + 79839232);             //  8,388,608
    int*            route      = (int*)(w + 88227840);               //    262,144
    int*            rows_list  = (int*)(w + 88489984);               //    266,240
    unsigned short* WrTh       = (unsigned short*)(w + 88756224);    //    524,288
    int*            rescue     = (int*)(w + 89280512);               //     32,768
    int*            meta       = (int*)(w + 89313280);               //      4,096
    const size_t WS_NEED = 89317376ULL;
    if (ws_size < WS_NEED) return;

    (void)hipMemsetAsync(meta, 0, 4096, stream);

    k_wtr    <<<64,   256, 0, stream>>>(W_root, WrTh);
    k_trW    <<<512,  256, 0, stream>>>(W_leaf, WlT);
    k_trpad  <<<256,  256, 0, stream>>>(W_ldec, WldT);
    k_trdec  <<<32,   256, 0, stream>>>(W_dec, WdT);
    k_root   <<<2048, 256, 0, stream>>>(x, WrTh, b_root, WdT, hbuf, logit_part);
    k_dec    <<<256,  256, 0, stream>>>(logit_part, b_dec, out, route, meta, rescue);
    k_rescue <<<8192, 256, 0, stream>>>(x, W_root, b_root, W_dec, b_dec, rescue, meta, out, route);
    k_count  <<<256,  256, 0, stream>>>(route, meta);
    k_scan   <<<1,    64,  0, stream>>>(meta);
    k_scatter<<<256,  256, 0, stream>>>(route, meta, rows_list);
    k_gemm2  <<<2080, 256, 0, stream>>>(hbuf, WlT, b_leaf, WldT, rows_list, meta, ldec_part);
    k_sel    <<<256,  256, 0, stream>>>(ldec_part, route, b_ldec, out);
}

// Round 15
// 257.227 us; speedup vs baseline: 1.1853x; 1.0193x over previous
//
#include <hip/hip_runtime.h>
#include <stdint.h>

#define DD   512
#define EE   8

typedef __bf16 bf16x8 __attribute__((ext_vector_type(8)));
typedef float  f32x4  __attribute__((ext_vector_type(4)));
typedef unsigned short u16x8 __attribute__((ext_vector_type(8)));

__device__ __forceinline__ unsigned short f2bf(float f) {  // RTNE
    union { float f; unsigned int i; } v; v.f = f;
    unsigned int x = v.i;
    x += 0x7fffu + ((x >> 16) & 1u);
    return (unsigned short)(x >> 16);
}
__device__ __forceinline__ void gload_lds16(const void* g, void* l) {
    __builtin_amdgcn_global_load_lds(
        (const __attribute__((address_space(1))) unsigned int*)g,
        (__attribute__((address_space(3))) unsigned int*)l, 16, 0, 0);
}
__device__ __forceinline__ f32x4 mfma_bf16(bf16x8 a, bf16x8 b, f32x4 c) {
    return __builtin_amdgcn_mfma_f32_16x16x32_bf16(a, b, c, 0, 0, 0);
}

// ---------- K0: merged prep — W_root^T, W_leaf^T, W_ldec pad^T, W_dec pad^T ----------
__global__ __launch_bounds__(256) void k_prep(
    const float* __restrict__ W_root, const float* __restrict__ W_leaf,
    const float* __restrict__ W_ldec, const float* __restrict__ W_dec,
    unsigned short* __restrict__ WrTh, unsigned short* __restrict__ WlT,
    unsigned short* __restrict__ WldT, unsigned short* __restrict__ WdT)
{
    __shared__ unsigned short tile[64][65];
    int bid = blockIdx.x;            // 864 = 64 (wtr) + 512 (trW) + 256 (trpad) + 32 (trdec)
    int t = threadIdx.x;
    if (bid < 576) {
        // transpose path: bid<64 -> W_root; else W_leaf expert (bid-64)>>6
        const float* src;
        unsigned short* dst;
        int tl;
        if (bid < 64) {
            src = W_root; dst = WrTh; tl = bid;
        } else {
            int e = (bid - 64) >> 6;
            src = W_leaf + (size_t)e * DD * DD;
            dst = WlT + (size_t)e * DD * DD;
            tl = (bid - 64) & 63;
        }
        int tr = tl >> 3, tc = tl & 7;
        #pragma unroll
        for (int j = 0; j < 16; j++) {
            int i2 = t + j * 256; int r = i2 >> 6, c = i2 & 63;
            tile[r][c] = f2bf(src[(size_t)(tr * 64 + r) * DD + tc * 64 + c]);
        }
        __syncthreads();
        #pragma unroll
        for (int j = 0; j < 16; j++) {
            int i2 = t + j * 256; int r = i2 >> 6, c = i2 & 63;
            dst[(size_t)(tc * 64 + r) * DD + tr * 64 + c] = tile[c][r];
        }
    } else if (bid < 832) {
        int idx = (bid - 576) * 256 + t;           // 65536: WldT [e][16][512]
        int e = idx >> 13, rem = idx & 8191;
        int o = rem >> 9, k = rem & 511;
        unsigned short v = 0;
        if (o < 8) v = f2bf(W_ldec[((size_t)e * DD + k) * EE + o]);
        WldT[idx] = v;
    } else {
        int idx = (bid - 832) * 256 + t;           // 8192: WdT [16][512]
        int o = idx >> 9, k = idx & 511;
        WdT[idx] = (o < 8) ? f2bf(W_dec[(size_t)k * EE + o]) : (unsigned short)0;
    }
}

// ---------- K1: bf16 MFMA root GEMM; double-buffered single-barrier K-loop (r13 best) ----------
// A staged as f32 via global_load_lds (XOR source/read swizzle); cvt at fragment read.
// B staged bf16 linear. One __syncthreads per K-step.
__global__ __launch_bounds__(256) void k_root(
    const float* __restrict__ x,
    const unsigned short* __restrict__ WrTh,
    const float* __restrict__ b_root,
    const unsigned short* __restrict__ WdT,
    unsigned short* __restrict__ hbuf,
    float* __restrict__ logit_part)          // [4][65536][8], p = cb
{
    __shared__ unsigned short smem[24576];       // 49152 B; loop dbuf; epi: lh[128][136]
    float* fA = (float*)&smem[0];                // 2 buffers: f32 idx 0 / 4096 (128x32 f32 each)
    unsigned short* bB = &smem[16384];           // 2 buffers: u16 idx 0 / 4096 (128x32 bf16 each)

    int bid = blockIdx.x;                         // 2048 = 512 mb * 4 cb
    int mb = (bid >> 5) * 8 + (bid & 7);          // XCD-swizzled
    int cb = (bid >> 3) & 3;
    int m0 = mb * 128, n0 = cb * 128;

    int t = threadIdx.x;
    int wid = t >> 6, lane = t & 63;
    int wr = wid >> 1, wc = wid & 1;
    int l15 = lane & 15, l4 = lane >> 4;

    // A staging: thread t covers rows (t>>3)+j*32, 16B (4 f32) at swizzled slot
    int arow = t >> 3;
    int aswz = ((t & 7) ^ (arow & 7)) * 4;        // f32 elems; involution with read side
    const float* srcA = x + (size_t)(m0 + arow) * DD + aswz;
    int adst = arow * 32 + aswz;                  // f32 index into A buffer
    // B staging: linear
    const unsigned short* srcB0 = WrTh + (size_t)(n0 + (t >> 2)) * DD + (t & 3) * 8;
    const unsigned short* srcB1 = srcB0 + (size_t)64 * DD;

    f32x4 acc[4][4];
    #pragma unroll
    for (int m = 0; m < 4; m++)
        #pragma unroll
        for (int n = 0; n < 4; n++) acc[m][n] = (f32x4){0.f, 0.f, 0.f, 0.f};

    // prologue: stage tile 0 into buffer 0
    #pragma unroll
    for (int j = 0; j < 4; j++)
        gload_lds16(srcA + (size_t)j * 32 * DD, fA + adst + j * 1024);
    gload_lds16(srcB0, bB + t * 8);
    gload_lds16(srcB1, bB + 2048 + t * 8);
    __syncthreads();

    for (int it = 0; it < 16; ++it) {
        int cur = it & 1;
        int ao = cur * 4096;                      // f32 elems
        int bo = cur * 4096;                      // u16 elems
        if (it < 15) {                            // stage next tile into other buffer
            int k0n = (it + 1) * 32;
            int aon = (cur ^ 1) * 4096, bon = (cur ^ 1) * 4096;
            #pragma unroll
            for (int j = 0; j < 4; j++)
                gload_lds16(srcA + (size_t)j * 32 * DD + k0n, fA + aon + adst + j * 1024);
            gload_lds16(srcB0 + k0n, bB + bon + t * 8);
            gload_lds16(srcB1 + k0n, bB + bon + 2048 + t * 8);
        }
        // A fragments: f32 swizzled reads + cvt
        bf16x8 fa[4], fb[4];
        #pragma unroll
        for (int m = 0; m < 4; m++) {
            int r = wr * 64 + m * 16 + l15;
            int s0 = (l4 * 2) ^ (r & 7), s1 = (l4 * 2 + 1) ^ (r & 7);
            f32x4 lo = *(const f32x4*)&fA[ao + r * 32 + s0 * 4];
            f32x4 hi = *(const f32x4*)&fA[ao + r * 32 + s1 * 4];
            #pragma unroll
            for (int j = 0; j < 4; j++) { fa[m][j] = (__bf16)lo[j]; fa[m][4 + j] = (__bf16)hi[j]; }
        }
        #pragma unroll
        for (int n = 0; n < 4; n++)
            fb[n] = *(const bf16x8*)&bB[bo + (wc * 64 + n * 16 + l15) * 32 + l4 * 8];
        #pragma unroll
        for (int m = 0; m < 4; m++)
            #pragma unroll
            for (int n = 0; n < 4; n++)
                acc[m][n] = mfma_bf16(fa[m], fb[n], acc[m][n]);
        __syncthreads();                          // drains vmcnt: next buffer ready
    }

    // epilogue 1: bias + relu -> h tile (bf16) in smem as lh[128][136]
    float bcol[4];
    #pragma unroll
    for (int n = 0; n < 4; n++) bcol[n] = b_root[n0 + wc * 64 + n * 16 + l15];
    #pragma unroll
    for (int n = 0; n < 4; n++) {
        int coll = wc * 64 + n * 16 + l15;
        #pragma unroll
        for (int m = 0; m < 4; m++) {
            int rl = wr * 64 + m * 16 + l4 * 4;
            #pragma unroll
            for (int i = 0; i < 4; i++) {
                float v = acc[m][n][i] + bcol[n];
                v = v > 0.f ? v : 0.f;
                smem[(rl + i) * 136 + coll] = f2bf(v);
            }
        }
    }
    __syncthreads();

    // epilogue 2a: vectorized h store from lh
    {
        int r = t >> 1, c0s = (t & 1) * 64;
        unsigned short* dst = hbuf + (size_t)(m0 + r) * DD + n0 + c0s;
        #pragma unroll
        for (int j = 0; j < 8; j++)
            *(u16x8*)(dst + j * 8) = *(const u16x8*)&smem[r * 136 + c0s + j * 8];
    }

    // epilogue 2b: logit partial = lh_tile @ W_dec[n0:n0+128][:] via MFMA
    f32x4 acc2[2];
    acc2[0] = (f32x4){0.f, 0.f, 0.f, 0.f};
    acc2[1] = (f32x4){0.f, 0.f, 0.f, 0.f};
    #pragma unroll
    for (int kk = 0; kk < 4; kk++) {
        bf16x8 bb = *(const bf16x8*)(WdT + (size_t)l15 * DD + n0 + kk * 32 + l4 * 8);
        #pragma unroll
        for (int m2 = 0; m2 < 2; m2++) {
            bf16x8 aa = *(const bf16x8*)&smem[(wid * 32 + m2 * 16 + l15) * 136 + kk * 32 + l4 * 8];
            acc2[m2] = mfma_bf16(aa, bb, acc2[m2]);
        }
    }
    if (l15 < 8) {
        #pragma unroll
        for (int m2 = 0; m2 < 2; m2++)
            #pragma unroll
            for (int i = 0; i < 4; i++) {
                int rowg = m0 + wid * 32 + m2 * 16 + l4 * 4 + i;
                logit_part[((size_t)cb * 65536 + rowg) * 8 + l15] = acc2[m2][i];
            }
    }
}

// ---------- K2: dec softmax + route + gap-flag + fused ballot count ----------
__global__ __launch_bounds__(256) void k_dec(
    const float* __restrict__ logit_part,
    const float* __restrict__ b_dec,
    float* __restrict__ out,
    int* __restrict__ route,
    int* __restrict__ meta,
    int* __restrict__ rescue_list)
{
    __shared__ int wcnt[4][8];
    int b = blockIdx.x * 256 + threadIdx.x;
    double lg[8];
    #pragma unroll
    for (int o = 0; o < 8; o++) lg[o] = (double)b_dec[o];
    #pragma unroll
    for (int ppp = 0; ppp < 4; ppp++) {        // fixed order: deterministic
        #pragma unroll
        for (int o = 0; o < 8; o++)
            lg[o] += (double)logit_part[((size_t)ppp * 65536 + b) * 8 + o];
    }
    double mx = -1e300, mx2 = -1e300; int idx = 0;
    #pragma unroll
    for (int o = 0; o < 8; o++) {
        if (lg[o] > mx) { mx2 = mx; mx = lg[o]; idx = o; }
        else if (lg[o] > mx2) mx2 = lg[o];
    }
    float ev[8], s = 0.f;
    #pragma unroll
    for (int o = 0; o < 8; o++) { ev[o] = expf((float)(lg[o] - mx)); s += ev[o]; }
    float inv = 1.f / s;
    float4 o0, o1;
    o0.x = ev[0]*inv; o0.y = ev[1]*inv; o0.z = ev[2]*inv; o0.w = ev[3]*inv;
    o1.x = ev[4]*inv; o1.y = ev[5]*inv; o1.z = ev[6]*inv; o1.w = ev[7]*inv;
    float4* op = (float4*)(out + (size_t)b * 16);
    op[0] = o0; op[1] = o1;
    route[b] = idx;
    if (mx - mx2 < 3e-3) {                     // near-tie (~8 sigma of bf16-GEMM logit err)
        int pos = atomicAdd(&meta[27], 1);
        if (pos < 8192) rescue_list[pos] = b;
    }
    // fused route count (pre-rescue; k_rescue adjusts on flips)
    int lane = threadIdx.x & 63, wv = threadIdx.x >> 6;
    #pragma unroll
    for (int ex = 0; ex < 8; ex++) {
        unsigned long long m = __ballot(idx == ex);
        if (lane == 0) wcnt[wv][ex] = __popcll(m);
    }
    __syncthreads();
    if (threadIdx.x < 8) {
        int ex = threadIdx.x;
        atomicAdd(&meta[ex], wcnt[0][ex] + wcnt[1][ex] + wcnt[2][ex] + wcnt[3][ex]);
    }
}

// ---------- K2b: exact f64 rescue (dec + route + count fixup) ----------
__global__ __launch_bounds__(256) void k_rescue(
    const float* __restrict__ x,
    const float* __restrict__ W_root,
    const float* __restrict__ b_root,
    const float* __restrict__ W_dec,
    const float* __restrict__ b_dec,
    const int* __restrict__ rescue_list,
    int* __restrict__ meta,
    float* __restrict__ out,
    int* __restrict__ route)
{
    int nresc = min(meta[27], 8192);
    if ((int)blockIdx.x >= nresc) return;
    int row = rescue_list[blockIdx.x];
    int t = threadIdx.x;

    __shared__ float xr[512];
    __shared__ double red[4][8];
    xr[t * 2]     = x[(size_t)row * DD + t * 2];
    xr[t * 2 + 1] = x[(size_t)row * DD + t * 2 + 1];
    __syncthreads();

    int d0 = t, d1 = t + 256;
    double a0 = 0.0, a1 = 0.0;
    for (int k = 0; k < DD; k++) {
        double xv = (double)xr[k];
        a0 += xv * (double)W_root[(size_t)k * DD + d0];
        a1 += xv * (double)W_root[(size_t)k * DD + d1];
    }
    double h0 = fmax(a0 + (double)b_root[d0], 0.0);
    double h1 = fmax(a1 + (double)b_root[d1], 0.0);
    double so[8];
    #pragma unroll
    for (int o = 0; o < 8; o++)
        so[o] = h0 * (double)W_dec[d0 * 8 + o] + h1 * (double)W_dec[d1 * 8 + o];
    #pragma unroll
    for (int d = 1; d < 64; d <<= 1)
        #pragma unroll
        for (int o = 0; o < 8; o++) so[o] += __shfl_xor(so[o], d, 64);
    if ((t & 63) == 0) {
        #pragma unroll
        for (int o = 0; o < 8; o++) red[t >> 6][o] = so[o];
    }
    __syncthreads();
    if (t == 0) {
        double lg[8]; double mx = -1e300; int idx = 0;
        #pragma unroll
        for (int o = 0; o < 8; o++) {
            lg[o] = red[0][o] + red[1][o] + red[2][o] + red[3][o] + (double)b_dec[o];
            if (lg[o] > mx) { mx = lg[o]; idx = o; }
        }
        double ev[8], s = 0.0;
        #pragma unroll
        for (int o = 0; o < 8; o++) { ev[o] = exp(lg[o] - mx); s += ev[o]; }
        double inv = 1.0 / s;
        float4 o0, o1;
        o0.x = (float)(ev[0]*inv); o0.y = (float)(ev[1]*inv);
        o0.z = (float)(ev[2]*inv); o0.w = (float)(ev[3]*inv);
        o1.x = (float)(ev[4]*inv); o1.y = (float)(ev[5]*inv);
        o1.z = (float)(ev[6]*inv); o1.w = (float)(ev[7]*inv);
        float4* op = (float4*)(out + (size_t)row * 16);
        op[0] = o0; op[1] = o1;
        int old = route[row];
        if (idx != old) {                        // count fixup on route flip
            atomicSub(&meta[old], 1);
            atomicAdd(&meta[idx], 1);
            route[row] = idx;
        }
    }
}

// ---------- K3: scan ----------
__global__ void k_scan(int* __restrict__ meta)
{
    if (threadIdx.x == 0 && blockIdx.x == 0) {
        int run = 0, rb = 0;
        for (int e = 0; e < 8; e++) {
            int c = meta[e];
            meta[16 + e] = run;
            meta[8 + e]  = run;
            int n = (c + 127) >> 7;
            for (int j = 0; j < n; j++) meta[32 + rb + j] = e | (j << 8);
            rb += n;
            run += n << 7;
        }
        meta[24] = rb;
    }
}

// ---------- K4: scatter — ballot-ranked, 8 atomics/block ----------
__global__ __launch_bounds__(256) void k_scatter(
    const int* __restrict__ route, int* __restrict__ meta, int* __restrict__ rows_list)
{
    __shared__ int wcnt[4][8];
    __shared__ int wbase[4][8];
    int b = blockIdx.x * 256 + threadIdx.x;
    int e = route[b];
    int lane = threadIdx.x & 63, wv = threadIdx.x >> 6;
    unsigned long long mymask = 0;
    #pragma unroll
    for (int ex = 0; ex < 8; ex++) {
        unsigned long long m = __ballot(e == ex);
        if (e == ex) mymask = m;
        if (lane == 0) wcnt[wv][ex] = __popcll(m);
    }
    int myrank = __popcll(mymask & ((1ULL << lane) - 1ULL));
    __syncthreads();
    if (threadIdx.x < 8) {
        int ex = threadIdx.x;
        int c0 = wcnt[0][ex], c1 = wcnt[1][ex], c2 = wcnt[2][ex], c3 = wcnt[3][ex];
        int base = atomicAdd(&meta[8 + ex], c0 + c1 + c2 + c3);
        wbase[0][ex] = base;
        wbase[1][ex] = base + c0;
        wbase[2][ex] = base + c0 + c1;
        wbase[3][ex] = base + c0 + c1 + c2;
    }
    __syncthreads();
    rows_list[wbase[wv][e] + myrank] = b;
}

// ---------- K5: grouped leaf GEMM; double-buffered single-barrier K-loop ----------
__global__ __launch_bounds__(256) void k_gemm2(
    const unsigned short* __restrict__ hbuf,
    const unsigned short* __restrict__ WlT,
    const float* __restrict__ b_leaf,
    const unsigned short* __restrict__ WldT,
    const int* __restrict__ rows_list,
    const int* __restrict__ meta,
    float* __restrict__ ldec_part)           // [4][65536][8]
{
    __shared__ unsigned short smem[17408];       // 34816 B; loop dbuf; epi: lh[128][136]
    // A buffers: u16 idx 0 / 4096;  B buffers: u16 idx 8192 / 12288 (128x32 bf16 each)

    int bid = blockIdx.x;
    int rbid = (bid >> 5) * 8 + (bid & 7);
    int cb = (bid >> 3) & 3;
    if (rbid >= meta[24]) return;
    int pk = meta[32 + rbid];
    int e = pk & 255, lrb = pk >> 8;
    int poff_e = meta[16 + e], cnt_e = meta[e];
    int n0 = cb * 128;

    int t = threadIdx.x;
    int wid = t >> 6, lane = t & 63;
    int wr = wid >> 1, wc = wid & 1;
    int l15 = lane & 15, l4 = lane >> 4;

    int slot0 = poff_e + lrb * 128 + (t >> 2);
    int slot1 = slot0 + 64;
    int lastv = poff_e + cnt_e - 1;
    int grow0 = rows_list[min(slot0, lastv)];    // clamp pad slots (idempotent recompute)
    int grow1 = rows_list[min(slot1, lastv)];
    const unsigned short* srcA0 = hbuf + (size_t)grow0 * DD + (t & 3) * 8;
    const unsigned short* srcA1 = hbuf + (size_t)grow1 * DD + (t & 3) * 8;
    const unsigned short* srcB0 = WlT + (size_t)e * DD * DD + (size_t)(n0 + (t >> 2)) * DD + (t & 3) * 8;
    const unsigned short* srcB1 = srcB0 + (size_t)64 * DD;

    f32x4 acc[4][4];
    #pragma unroll
    for (int m = 0; m < 4; m++)
        #pragma unroll
        for (int n = 0; n < 4; n++) acc[m][n] = (f32x4){0.f, 0.f, 0.f, 0.f};

    // prologue: stage tile 0 into buffer 0
    gload_lds16(srcA0, &smem[t * 8]);
    gload_lds16(srcA1, &smem[2048 + t * 8]);
    gload_lds16(srcB0, &smem[8192 + t * 8]);
    gload_lds16(srcB1, &smem[8192 + 2048 + t * 8]);
    __syncthreads();

    for (int it = 0; it < 16; ++it) {
        int cur = it & 1;
        int ao = cur * 4096, bo = 8192 + cur * 4096;
        if (it < 15) {
            int k0n = (it + 1) * 32;
            int aon = (cur ^ 1) * 4096, bon = 8192 + (cur ^ 1) * 4096;
            gload_lds16(srcA0 + k0n, &smem[aon + t * 8]);
            gload_lds16(srcA1 + k0n, &smem[aon + 2048 + t * 8]);
            gload_lds16(srcB0 + k0n, &smem[bon + t * 8]);
            gload_lds16(srcB1 + k0n, &smem[bon + 2048 + t * 8]);
        }
        bf16x8 af[4], bfr[4];
        #pragma unroll
        for (int m = 0; m < 4; m++)
            af[m] = *(const bf16x8*)&smem[ao + (wr * 64 + m * 16 + l15) * 32 + l4 * 8];
        #pragma unroll
        for (int n = 0; n < 4; n++)
            bfr[n] = *(const bf16x8*)&smem[bo + (wc * 64 + n * 16 + l15) * 32 + l4 * 8];
        #pragma unroll
        for (int m = 0; m < 4; m++)
            #pragma unroll
            for (int n = 0; n < 4; n++)
                acc[m][n] = mfma_bf16(af[m], bfr[n], acc[m][n]);
        __syncthreads();
    }

    // epilogue 1: bias + relu -> lh tile (bf16) in smem
    float bcol[4];
    #pragma unroll
    for (int n = 0; n < 4; n++) bcol[n] = b_leaf[(size_t)e * DD + n0 + wc * 64 + n * 16 + l15];
    #pragma unroll
    for (int n = 0; n < 4; n++) {
        int coll = wc * 64 + n * 16 + l15;
        #pragma unroll
        for (int m = 0; m < 4; m++) {
            int rl = wr * 64 + m * 16 + l4 * 4;
            #pragma unroll
            for (int i = 0; i < 4; i++) {
                float v = acc[m][n][i] + bcol[n];
                v = v > 0.f ? v : 0.f;
                smem[(rl + i) * 136 + coll] = f2bf(v);
            }
        }
    }
    __syncthreads();

    // epilogue 2: ldec partial = lh_tile @ W_ldec[e][n0:n0+128][:] via MFMA
    f32x4 acc2[2];
    acc2[0] = (f32x4){0.f, 0.f, 0.f, 0.f};
    acc2[1] = (f32x4){0.f, 0.f, 0.f, 0.f};
    #pragma unroll
    for (int kk = 0; kk < 4; kk++) {
        bf16x8 bb = *(const bf16x8*)(WldT + ((size_t)e * 16 + l15) * DD + n0 + kk * 32 + l4 * 8);
        #pragma unroll
        for (int m2 = 0; m2 < 2; m2++) {
            bf16x8 aa = *(const bf16x8*)&smem[(wid * 32 + m2 * 16 + l15) * 136 + kk * 32 + l4 * 8];
            acc2[m2] = mfma_bf16(aa, bb, acc2[m2]);
        }
    }
    if (l15 < 8) {
        #pragma unroll
        for (int m2 = 0; m2 < 2; m2++)
            #pragma unroll
            for (int i = 0; i < 4; i++) {
                int rl = wid * 32 + m2 * 16 + l4 * 4 + i;
                int s = min(poff_e + lrb * 128 + rl, lastv);
                int brow = rows_list[s];             // pad slots: duplicate identical writes
                ldec_part[((size_t)cb * 65536 + brow) * 8 + l15] = acc2[m2][i];
            }
    }
}

// ---------- K6: sel softmax ----------
__global__ __launch_bounds__(256) void k_sel(
    const float* __restrict__ ldec_part,
    const int* __restrict__ route,
    const float* __restrict__ b_ldec,
    float* __restrict__ out)
{
    int b = blockIdx.x * 256 + threadIdx.x;
    int e = route[b];
    float lg[8];
    #pragma unroll
    for (int o = 0; o < 8; o++) lg[o] = b_ldec[e * 8 + o];
    #pragma unroll
    for (int p = 0; p < 4; p++) {
        const float4* ap = (const float4*)(ldec_part + ((size_t)p * 65536 + b) * 8);
        float4 a0 = ap[0], a1 = ap[1];
        lg[0]+=a0.x; lg[1]+=a0.y; lg[2]+=a0.z; lg[3]+=a0.w;
        lg[4]+=a1.x; lg[5]+=a1.y; lg[6]+=a1.z; lg[7]+=a1.w;
    }
    float mx = -1e30f;
    #pragma unroll
    for (int o = 0; o < 8; o++) mx = fmaxf(mx, lg[o]);
    float ev[8], s = 0.f;
    #pragma unroll
    for (int o = 0; o < 8; o++) { ev[o] = expf(lg[o] - mx); s += ev[o]; }
    float inv = 1.f / s;
    float4 o0, o1;
    o0.x = ev[0]*inv; o0.y = ev[1]*inv; o0.z = ev[2]*inv; o0.w = ev[3]*inv;
    o1.x = ev[4]*inv; o1.y = ev[5]*inv; o1.z = ev[6]*inv; o1.w = ev[7]*inv;
    float4* op = (float4*)(out + (size_t)b * 16 + 8);
    op[0] = o0; op[1] = o1;
}

extern "C" void kernel_launch(void* const* d_in, const int* in_sizes, int n_in,
                              void* d_out, int out_size, void* d_ws, size_t ws_size,
                              hipStream_t stream)
{
    const float* x      = (const float*)d_in[0];
    const float* W_root = (const float*)d_in[1];
    const float* b_root = (const float*)d_in[2];
    const float* W_dec  = (const float*)d_in[3];
    const float* b_dec  = (const float*)d_in[4];
    const float* W_leaf = (const float*)d_in[5];
    const float* b_leaf = (const float*)d_in[6];
    const float* W_ldec = (const float*)d_in[7];
    const float* b_ldec = (const float*)d_in[8];
    float* out = (float*)d_out;

    char* w = (char*)d_ws;
    unsigned short* hbuf       = (unsigned short*)(w);               // 67,108,864
    float*          logit_part = (float*)(w + 67108864);             //  8,388,608
    unsigned short* WlT        = (unsigned short*)(w + 75497472);    //  4,194,304
    unsigned short* WldT       = (unsigned short*)(w + 79691776);    //    131,072
    unsigned short* WdT        = (unsigned short*)(w + 79822848);    //     16,384
    float*          ldec_part  = (float*)(w + 79839232);             //  8,388,608
    int*            route      = (int*)(w + 88227840);               //    262,144
    int*            rows_list  = (int*)(w + 88489984);               //    266,240
    unsigned short* WrTh       = (unsigned short*)(w + 88756224);    //    524,288
    int*            rescue     = (int*)(w + 89280512);               //     32,768
    int*            meta       = (int*)(w + 89313280);               //      4,096
    const size_t WS_NEED = 89317376ULL;
    if (ws_size < WS_NEED) return;

    (void)hipMemsetAsync(meta, 0, 4096, stream);

    k_prep   <<<864,  256, 0, stream>>>(W_root, W_leaf, W_ldec, W_dec, WrTh, WlT, WldT, WdT);
    k_root   <<<2048, 256, 0, stream>>>(x, WrTh, b_root, WdT, hbuf, logit_part);
    k_dec    <<<256,  256, 0, stream>>>(logit_part, b_dec, out, route, meta, rescue);
    k_rescue <<<8192, 256, 0, stream>>>(x, W_root, b_root, W_dec, b_dec, rescue, meta, out, route);
    k_scan   <<<1,    64,  0, stream>>>(meta);
    k_scatter<<<256,  256, 0, stream>>>(route, meta, rows_list);
    k_gemm2  <<<2080, 256, 0, stream>>>(hbuf, WlT, b_leaf, WldT, rows_list, meta, ldec_part);
    k_sel    <<<256,  256, 0, stream>>>(ldec_part, route, b_ldec, out);
}

// Round 16
// 251.241 us; speedup vs baseline: 1.2136x; 1.0238x over previous
//
#include <hip/hip_runtime.h>
#include <stdint.h>

#define DD   512
#define EE   8

typedef __bf16 bf16x8 __attribute__((ext_vector_type(8)));
typedef float  f32x4  __attribute__((ext_vector_type(4)));
typedef unsigned short u16x8 __attribute__((ext_vector_type(8)));

__device__ __forceinline__ unsigned short f2bf(float f) {  // RTNE
    union { float f; unsigned int i; } v; v.f = f;
    unsigned int x = v.i;
    x += 0x7fffu + ((x >> 16) & 1u);
    return (unsigned short)(x >> 16);
}
__device__ __forceinline__ void gload_lds16(const void* g, void* l) {
    __builtin_amdgcn_global_load_lds(
        (const __attribute__((address_space(1))) unsigned int*)g,
        (__attribute__((address_space(3))) unsigned int*)l, 16, 0, 0);
}
__device__ __forceinline__ f32x4 mfma_bf16(bf16x8 a, bf16x8 b, f32x4 c) {
    return __builtin_amdgcn_mfma_f32_16x16x32_bf16(a, b, c, 0, 0, 0);
}

// ---------- K0: merged prep — W_root^T, W_leaf^T, W_ldec pad^T, W_dec pad^T ----------
__global__ __launch_bounds__(256) void k_prep(
    const float* __restrict__ W_root, const float* __restrict__ W_leaf,
    const float* __restrict__ W_ldec, const float* __restrict__ W_dec,
    unsigned short* __restrict__ WrTh, unsigned short* __restrict__ WlT,
    unsigned short* __restrict__ WldT, unsigned short* __restrict__ WdT)
{
    __shared__ unsigned short tile[64][65];
    int bid = blockIdx.x;            // 864 = 64 (wtr) + 512 (trW) + 256 (trpad) + 32 (trdec)
    int t = threadIdx.x;
    if (bid < 576) {
        const float* src;
        unsigned short* dst;
        int tl;
        if (bid < 64) {
            src = W_root; dst = WrTh; tl = bid;
        } else {
            int e = (bid - 64) >> 6;
            src = W_leaf + (size_t)e * DD * DD;
            dst = WlT + (size_t)e * DD * DD;
            tl = (bid - 64) & 63;
        }
        int tr = tl >> 3, tc = tl & 7;
        #pragma unroll
        for (int j = 0; j < 16; j++) {
            int i2 = t + j * 256; int r = i2 >> 6, c = i2 & 63;
            tile[r][c] = f2bf(src[(size_t)(tr * 64 + r) * DD + tc * 64 + c]);
        }
        __syncthreads();
        #pragma unroll
        for (int j = 0; j < 16; j++) {
            int i2 = t + j * 256; int r = i2 >> 6, c = i2 & 63;
            dst[(size_t)(tc * 64 + r) * DD + tr * 64 + c] = tile[c][r];
        }
    } else if (bid < 832) {
        int idx = (bid - 576) * 256 + t;           // 65536: WldT [e][16][512]
        int e = idx >> 13, rem = idx & 8191;
        int o = rem >> 9, k = rem & 511;
        unsigned short v = 0;
        if (o < 8) v = f2bf(W_ldec[((size_t)e * DD + k) * EE + o]);
        WldT[idx] = v;
    } else {
        int idx = (bid - 832) * 256 + t;           // 8192: WdT [16][512]
        int o = idx >> 9, k = idx & 511;
        WdT[idx] = (o < 8) ? f2bf(W_dec[(size_t)k * EE + o]) : (unsigned short)0;
    }
}

// ---------- K1: bf16 MFMA root GEMM; BM=256, 512 threads, dbuf single-barrier K-loop ----------
// A staged as f32 via global_load_lds (pre-swizzled source, linear LDS); cvt at fragment read.
// B staged bf16 linear. One __syncthreads per K-step.
__global__ __launch_bounds__(512) void k_root(
    const float* __restrict__ x,
    const unsigned short* __restrict__ WrTh,
    const float* __restrict__ b_root,
    const unsigned short* __restrict__ WdT,
    unsigned short* __restrict__ hbuf,
    float* __restrict__ logit_part)          // [4][65536][8], p = cb
{
    __shared__ unsigned short smem[40960];       // 81920 B; A dbuf 2x32KB + B dbuf 2x8KB; epi lh[256][136]=69632B
    float* fA = (float*)&smem[0];                // f32 buffers at idx 0 / 8192 (256x32 f32 each)
    unsigned short* bB = &smem[32768];           // u16 buffers at idx 0 / 4096 (128x32 bf16 each)

    int bid = blockIdx.x;                         // 1024 = 256 mb * 4 cb
    int mb = (bid >> 5) * 8 + (bid & 7);          // XCD-swizzled: 4 cb of same mb on one XCD
    int cb = (bid >> 3) & 3;
    int m0 = mb * 256, n0 = cb * 128;

    int t = threadIdx.x;
    int wid = t >> 6, lane = t & 63;
    int wr = wid >> 1, wc = wid & 1;              // wr 0..3 (64-row quarters), wc 0..1
    int l15 = lane & 15, l4 = lane >> 4;

    // A staging: thread t covers rows (t>>3)+j*64 (j=0..3), 16B at pre-swizzled k-slot
    int arow = t >> 3;                            // 0..63
    int aswz = ((t & 7) ^ (arow & 7)) * 4;        // f32 elems; involution with read side
    const float* srcA = x + (size_t)(m0 + arow) * DD + aswz;
    int adst = arow * 32 + aswz;
    // B staging: 512 threads x 16B = full 128x32 bf16 tile in one issue
    const unsigned short* srcB = WrTh + (size_t)(n0 + (t >> 2)) * DD + (t & 3) * 8;

    f32x4 acc[4][4];
    #pragma unroll
    for (int m = 0; m < 4; m++)
        #pragma unroll
        for (int n = 0; n < 4; n++) acc[m][n] = (f32x4){0.f, 0.f, 0.f, 0.f};

    // prologue: stage tile 0 into buffer 0
    #pragma unroll
    for (int j = 0; j < 4; j++)
        gload_lds16(srcA + (size_t)j * 64 * DD, fA + adst + j * 2048);
    gload_lds16(srcB, bB + t * 8);
    __syncthreads();

    for (int it = 0; it < 16; ++it) {
        int cur = it & 1;
        int ao = cur * 8192;                      // f32 elems
        int bo = cur * 4096;                      // u16 elems
        if (it < 15) {                            // stage next tile into other buffer
            int k0n = (it + 1) * 32;
            int aon = (cur ^ 1) * 8192, bon = (cur ^ 1) * 4096;
            #pragma unroll
            for (int j = 0; j < 4; j++)
                gload_lds16(srcA + (size_t)j * 64 * DD + k0n, fA + aon + adst + j * 2048);
            gload_lds16(srcB + k0n, bB + bon + t * 8);
        }
        // A fragments: f32 swizzled reads + cvt
        bf16x8 fa[4], fb[4];
        #pragma unroll
        for (int m = 0; m < 4; m++) {
            int r = wr * 64 + m * 16 + l15;       // 0..255
            int s0 = (l4 * 2) ^ (r & 7), s1 = (l4 * 2 + 1) ^ (r & 7);
            f32x4 lo = *(const f32x4*)&fA[ao + r * 32 + s0 * 4];
            f32x4 hi = *(const f32x4*)&fA[ao + r * 32 + s1 * 4];
            #pragma unroll
            for (int j = 0; j < 4; j++) { fa[m][j] = (__bf16)lo[j]; fa[m][4 + j] = (__bf16)hi[j]; }
        }
        #pragma unroll
        for (int n = 0; n < 4; n++)
            fb[n] = *(const bf16x8*)&bB[bo + (wc * 64 + n * 16 + l15) * 32 + l4 * 8];
        #pragma unroll
        for (int m = 0; m < 4; m++)
            #pragma unroll
            for (int n = 0; n < 4; n++)
                acc[m][n] = mfma_bf16(fa[m], fb[n], acc[m][n]);
        __syncthreads();                          // drains vmcnt: next buffer ready
    }

    // epilogue 1: bias + relu -> h tile (bf16) in smem as lh[256][136]
    float bcol[4];
    #pragma unroll
    for (int n = 0; n < 4; n++) bcol[n] = b_root[n0 + wc * 64 + n * 16 + l15];
    #pragma unroll
    for (int n = 0; n < 4; n++) {
        int coll = wc * 64 + n * 16 + l15;
        #pragma unroll
        for (int m = 0; m < 4; m++) {
            int rl = wr * 64 + m * 16 + l4 * 4;
            #pragma unroll
            for (int i = 0; i < 4; i++) {
                float v = acc[m][n][i] + bcol[n];
                v = v > 0.f ? v : 0.f;
                smem[(rl + i) * 136 + coll] = f2bf(v);
            }
        }
    }
    __syncthreads();

    // epilogue 2a: vectorized h store from lh (256 rows x 128 cols)
    {
        int r = t >> 1, c0s = (t & 1) * 64;
        unsigned short* dst = hbuf + (size_t)(m0 + r) * DD + n0 + c0s;
        #pragma unroll
        for (int j = 0; j < 8; j++)
            *(u16x8*)(dst + j * 8) = *(const u16x8*)&smem[r * 136 + c0s + j * 8];
    }

    // epilogue 2b: logit partial = lh_tile @ W_dec[n0:n0+128][:] via MFMA (8 waves x 32 rows)
    f32x4 acc2[2];
    acc2[0] = (f32x4){0.f, 0.f, 0.f, 0.f};
    acc2[1] = (f32x4){0.f, 0.f, 0.f, 0.f};
    #pragma unroll
    for (int kk = 0; kk < 4; kk++) {
        bf16x8 bb = *(const bf16x8*)(WdT + (size_t)l15 * DD + n0 + kk * 32 + l4 * 8);
        #pragma unroll
        for (int m2 = 0; m2 < 2; m2++) {
            bf16x8 aa = *(const bf16x8*)&smem[(wid * 32 + m2 * 16 + l15) * 136 + kk * 32 + l4 * 8];
            acc2[m2] = mfma_bf16(aa, bb, acc2[m2]);
        }
    }
    if (l15 < 8) {
        #pragma unroll
        for (int m2 = 0; m2 < 2; m2++)
            #pragma unroll
            for (int i = 0; i < 4; i++) {
                int rowg = m0 + wid * 32 + m2 * 16 + l4 * 4 + i;
                logit_part[((size_t)cb * 65536 + rowg) * 8 + l15] = acc2[m2][i];
            }
    }
}

// ---------- K2: dec softmax + route + gap-flag + fused ballot count ----------
__global__ __launch_bounds__(256) void k_dec(
    const float* __restrict__ logit_part,
    const float* __restrict__ b_dec,
    float* __restrict__ out,
    int* __restrict__ route,
    int* __restrict__ meta,
    int* __restrict__ rescue_list)
{
    __shared__ int wcnt[4][8];
    int b = blockIdx.x * 256 + threadIdx.x;
    double lg[8];
    #pragma unroll
    for (int o = 0; o < 8; o++) lg[o] = (double)b_dec[o];
    #pragma unroll
    for (int ppp = 0; ppp < 4; ppp++) {        // fixed order: deterministic
        #pragma unroll
        for (int o = 0; o < 8; o++)
            lg[o] += (double)logit_part[((size_t)ppp * 65536 + b) * 8 + o];
    }
    double mx = -1e300, mx2 = -1e300; int idx = 0;
    #pragma unroll
    for (int o = 0; o < 8; o++) {
        if (lg[o] > mx) { mx2 = mx; mx = lg[o]; idx = o; }
        else if (lg[o] > mx2) mx2 = lg[o];
    }
    float ev[8], s = 0.f;
    #pragma unroll
    for (int o = 0; o < 8; o++) { ev[o] = expf((float)(lg[o] - mx)); s += ev[o]; }
    float inv = 1.f / s;
    float4 o0, o1;
    o0.x = ev[0]*inv; o0.y = ev[1]*inv; o0.z = ev[2]*inv; o0.w = ev[3]*inv;
    o1.x = ev[4]*inv; o1.y = ev[5]*inv; o1.z = ev[6]*inv; o1.w = ev[7]*inv;
    float4* op = (float4*)(out + (size_t)b * 16);
    op[0] = o0; op[1] = o1;
    route[b] = idx;
    if (mx - mx2 < 3e-3) {                     // near-tie (~8 sigma of bf16-GEMM logit err)
        int pos = atomicAdd(&meta[27], 1);
        if (pos < 8192) rescue_list[pos] = b;
    }
    // fused route count (pre-rescue; k_rescue adjusts on flips)
    int lane = threadIdx.x & 63, wv = threadIdx.x >> 6;
    #pragma unroll
    for (int ex = 0; ex < 8; ex++) {
        unsigned long long m = __ballot(idx == ex);
        if (lane == 0) wcnt[wv][ex] = __popcll(m);
    }
    __syncthreads();
    if (threadIdx.x < 8) {
        int ex = threadIdx.x;
        atomicAdd(&meta[ex], wcnt[0][ex] + wcnt[1][ex] + wcnt[2][ex] + wcnt[3][ex]);
    }
}

// ---------- K2b: exact f64 rescue (dec + route + count fixup) ----------
__global__ __launch_bounds__(256) void k_rescue(
    const float* __restrict__ x,
    const float* __restrict__ W_root,
    const float* __restrict__ b_root,
    const float* __restrict__ W_dec,
    const float* __restrict__ b_dec,
    const int* __restrict__ rescue_list,
    int* __restrict__ meta,
    float* __restrict__ out,
    int* __restrict__ route)
{
    int nresc = min(meta[27], 8192);
    if ((int)blockIdx.x >= nresc) return;
    int row = rescue_list[blockIdx.x];
    int t = threadIdx.x;

    __shared__ float xr[512];
    __shared__ double red[4][8];
    xr[t * 2]     = x[(size_t)row * DD + t * 2];
    xr[t * 2 + 1] = x[(size_t)row * DD + t * 2 + 1];
    __syncthreads();

    int d0 = t, d1 = t + 256;
    double a0 = 0.0, a1 = 0.0;
    for (int k = 0; k < DD; k++) {
        double xv = (double)xr[k];
        a0 += xv * (double)W_root[(size_t)k * DD + d0];
        a1 += xv * (double)W_root[(size_t)k * DD + d1];
    }
    double h0 = fmax(a0 + (double)b_root[d0], 0.0);
    double h1 = fmax(a1 + (double)b_root[d1], 0.0);
    double so[8];
    #pragma unroll
    for (int o = 0; o < 8; o++)
        so[o] = h0 * (double)W_dec[d0 * 8 + o] + h1 * (double)W_dec[d1 * 8 + o];
    #pragma unroll
    for (int d = 1; d < 64; d <<= 1)
        #pragma unroll
        for (int o = 0; o < 8; o++) so[o] += __shfl_xor(so[o], d, 64);
    if ((t & 63) == 0) {
        #pragma unroll
        for (int o = 0; o < 8; o++) red[t >> 6][o] = so[o];
    }
    __syncthreads();
    if (t == 0) {
        double lg[8]; double mx = -1e300; int idx = 0;
        #pragma unroll
        for (int o = 0; o < 8; o++) {
            lg[o] = red[0][o] + red[1][o] + red[2][o] + red[3][o] + (double)b_dec[o];
            if (lg[o] > mx) { mx = lg[o]; idx = o; }
        }
        double ev[8], s = 0.0;
        #pragma unroll
        for (int o = 0; o < 8; o++) { ev[o] = exp(lg[o] - mx); s += ev[o]; }
        double inv = 1.0 / s;
        float4 o0, o1;
        o0.x = (float)(ev[0]*inv); o0.y = (float)(ev[1]*inv);
        o0.z = (float)(ev[2]*inv); o0.w = (float)(ev[3]*inv);
        o1.x = (float)(ev[4]*inv); o1.y = (float)(ev[5]*inv);
        o1.z = (float)(ev[6]*inv); o1.w = (float)(ev[7]*inv);
        float4* op = (float4*)(out + (size_t)row * 16);
        op[0] = o0; op[1] = o1;
        int old = route[row];
        if (idx != old) {                        // count fixup on route flip
            atomicSub(&meta[old], 1);
            atomicAdd(&meta[idx], 1);
            route[row] = idx;
        }
    }
}

// ---------- K3: scan ----------
__global__ void k_scan(int* __restrict__ meta)
{
    if (threadIdx.x == 0 && blockIdx.x == 0) {
        int run = 0, rb = 0;
        for (int e = 0; e < 8; e++) {
            int c = meta[e];
            meta[16 + e] = run;
            meta[8 + e]  = run;
            int n = (c + 127) >> 7;
            for (int j = 0; j < n; j++) meta[32 + rb + j] = e | (j << 8);
            rb += n;
            run += n << 7;
        }
        meta[24] = rb;
    }
}

// ---------- K4: scatter — ballot-ranked, 8 atomics/block ----------
__global__ __launch_bounds__(256) void k_scatter(
    const int* __restrict__ route, int* __restrict__ meta, int* __restrict__ rows_list)
{
    __shared__ int wcnt[4][8];
    __shared__ int wbase[4][8];
    int b = blockIdx.x * 256 + threadIdx.x;
    int e = route[b];
    int lane = threadIdx.x & 63, wv = threadIdx.x >> 6;
    unsigned long long mymask = 0;
    #pragma unroll
    for (int ex = 0; ex < 8; ex++) {
        unsigned long long m = __ballot(e == ex);
        if (e == ex) mymask = m;
        if (lane == 0) wcnt[wv][ex] = __popcll(m);
    }
    int myrank = __popcll(mymask & ((1ULL << lane) - 1ULL));
    __syncthreads();
    if (threadIdx.x < 8) {
        int ex = threadIdx.x;
        int c0 = wcnt[0][ex], c1 = wcnt[1][ex], c2 = wcnt[2][ex], c3 = wcnt[3][ex];
        int base = atomicAdd(&meta[8 + ex], c0 + c1 + c2 + c3);
        wbase[0][ex] = base;
        wbase[1][ex] = base + c0;
        wbase[2][ex] = base + c0 + c1;
        wbase[3][ex] = base + c0 + c1 + c2;
    }
    __syncthreads();
    rows_list[wbase[wv][e] + myrank] = b;
}

// ---------- K5: grouped leaf GEMM; double-buffered single-barrier K-loop ----------
__global__ __launch_bounds__(256) void k_gemm2(
    const unsigned short* __restrict__ hbuf,
    const unsigned short* __restrict__ WlT,
    const float* __restrict__ b_leaf,
    const unsigned short* __restrict__ WldT,
    const int* __restrict__ rows_list,
    const int* __restrict__ meta,
    float* __restrict__ ldec_part)           // [4][65536][8]
{
    __shared__ unsigned short smem[17408];       // 34816 B; loop dbuf; epi: lh[128][136]
    // A buffers: u16 idx 0 / 4096;  B buffers: u16 idx 8192 / 12288 (128x32 bf16 each)

    int bid = blockIdx.x;
    int rbid = (bid >> 5) * 8 + (bid & 7);
    int cb = (bid >> 3) & 3;
    if (rbid >= meta[24]) return;
    int pk = meta[32 + rbid];
    int e = pk & 255, lrb = pk >> 8;
    int poff_e = meta[16 + e], cnt_e = meta[e];
    int n0 = cb * 128;

    int t = threadIdx.x;
    int wid = t >> 6, lane = t & 63;
    int wr = wid >> 1, wc = wid & 1;
    int l15 = lane & 15, l4 = lane >> 4;

    int slot0 = poff_e + lrb * 128 + (t >> 2);
    int slot1 = slot0 + 64;
    int lastv = poff_e + cnt_e - 1;
    int grow0 = rows_list[min(slot0, lastv)];    // clamp pad slots (idempotent recompute)
    int grow1 = rows_list[min(slot1, lastv)];
    const unsigned short* srcA0 = hbuf + (size_t)grow0 * DD + (t & 3) * 8;
    const unsigned short* srcA1 = hbuf + (size_t)grow1 * DD + (t & 3) * 8;
    const unsigned short* srcB0 = WlT + (size_t)e * DD * DD + (size_t)(n0 + (t >> 2)) * DD + (t & 3) * 8;
    const unsigned short* srcB1 = srcB0 + (size_t)64 * DD;

    f32x4 acc[4][4];
    #pragma unroll
    for (int m = 0; m < 4; m++)
        #pragma unroll
        for (int n = 0; n < 4; n++) acc[m][n] = (f32x4){0.f, 0.f, 0.f, 0.f};

    // prologue: stage tile 0 into buffer 0
    gload_lds16(srcA0, &smem[t * 8]);
    gload_lds16(srcA1, &smem[2048 + t * 8]);
    gload_lds16(srcB0, &smem[8192 + t * 8]);
    gload_lds16(srcB1, &smem[8192 + 2048 + t * 8]);
    __syncthreads();

    for (int it = 0; it < 16; ++it) {
        int cur = it & 1;
        int ao = cur * 4096, bo = 8192 + cur * 4096;
        if (it < 15) {
            int k0n = (it + 1) * 32;
            int aon = (cur ^ 1) * 4096, bon = 8192 + (cur ^ 1) * 4096;
            gload_lds16(srcA0 + k0n, &smem[aon + t * 8]);
            gload_lds16(srcA1 + k0n, &smem[aon + 2048 + t * 8]);
            gload_lds16(srcB0 + k0n, &smem[bon + t * 8]);
            gload_lds16(srcB1 + k0n, &smem[bon + 2048 + t * 8]);
        }
        bf16x8 af[4], bfr[4];
        #pragma unroll
        for (int m = 0; m < 4; m++)
            af[m] = *(const bf16x8*)&smem[ao + (wr * 64 + m * 16 + l15) * 32 + l4 * 8];
        #pragma unroll
        for (int n = 0; n < 4; n++)
            bfr[n] = *(const bf16x8*)&smem[bo + (wc * 64 + n * 16 + l15) * 32 + l4 * 8];
        #pragma unroll
        for (int m = 0; m < 4; m++)
            #pragma unroll
            for (int n = 0; n < 4; n++)
                acc[m][n] = mfma_bf16(af[m], bfr[n], acc[m][n]);
        __syncthreads();
    }

    // epilogue 1: bias + relu -> lh tile (bf16) in smem
    float bcol[4];
    #pragma unroll
    for (int n = 0; n < 4; n++) bcol[n] = b_leaf[(size_t)e * DD + n0 + wc * 64 + n * 16 + l15];
    #pragma unroll
    for (int n = 0; n < 4; n++) {
        int coll = wc * 64 + n * 16 + l15;
        #pragma unroll
        for (int m = 0; m < 4; m++) {
            int rl = wr * 64 + m * 16 + l4 * 4;
            #pragma unroll
            for (int i = 0; i < 4; i++) {
                float v = acc[m][n][i] + bcol[n];
                v = v > 0.f ? v : 0.f;
                smem[(rl + i) * 136 + coll] = f2bf(v);
            }
        }
    }
    __syncthreads();

    // epilogue 2: ldec partial = lh_tile @ W_ldec[e][n0:n0+128][:] via MFMA
    f32x4 acc2[2];
    acc2[0] = (f32x4){0.f, 0.f, 0.f, 0.f};
    acc2[1] = (f32x4){0.f, 0.f, 0.f, 0.f};
    #pragma unroll
    for (int kk = 0; kk < 4; kk++) {
        bf16x8 bb = *(const bf16x8*)(WldT + ((size_t)e * 16 + l15) * DD + n0 + kk * 32 + l4 * 8);
        #pragma unroll
        for (int m2 = 0; m2 < 2; m2++) {
            bf16x8 aa = *(const bf16x8*)&smem[(wid * 32 + m2 * 16 + l15) * 136 + kk * 32 + l4 * 8];
            acc2[m2] = mfma_bf16(aa, bb, acc2[m2]);
        }
    }
    if (l15 < 8) {
        #pragma unroll
        for (int m2 = 0; m2 < 2; m2++)
            #pragma unroll
            for (int i = 0; i < 4; i++) {
                int rl = wid * 32 + m2 * 16 + l4 * 4 + i;
                int s = min(poff_e + lrb * 128 + rl, lastv);
                int brow = rows_list[s];             // pad slots: duplicate identical writes
                ldec_part[((size_t)cb * 65536 + brow) * 8 + l15] = acc2[m2][i];
            }
    }
}

// ---------- K6: sel softmax ----------
__global__ __launch_bounds__(256) void k_sel(
    const float* __restrict__ ldec_part,
    const int* __restrict__ route,
    const float* __restrict__ b_ldec,
    float* __restrict__ out)
{
    int b = blockIdx.x * 256 + threadIdx.x;
    int e = route[b];
    float lg[8];
    #pragma unroll
    for (int o = 0; o < 8; o++) lg[o] = b_ldec[e * 8 + o];
    #pragma unroll
    for (int p = 0; p < 4; p++) {
        const float4* ap = (const float4*)(ldec_part + ((size_t)p * 65536 + b) * 8);
        float4 a0 = ap[0], a1 = ap[1];
        lg[0]+=a0.x; lg[1]+=a0.y; lg[2]+=a0.z; lg[3]+=a0.w;
        lg[4]+=a1.x; lg[5]+=a1.y; lg[6]+=a1.z; lg[7]+=a1.w;
    }
    float mx = -1e30f;
    #pragma unroll
    for (int o = 0; o < 8; o++) mx = fmaxf(mx, lg[o]);
    float ev[8], s = 0.f;
    #pragma unroll
    for (int o = 0; o < 8; o++) { ev[o] = expf(lg[o] - mx); s += ev[o]; }
    float inv = 1.f / s;
    float4 o0, o1;
    o0.x = ev[0]*inv; o0.y = ev[1]*inv; o0.z = ev[2]*inv; o0.w = ev[3]*inv;
    o1.x = ev[4]*inv; o1.y = ev[5]*inv; o1.z = ev[6]*inv; o1.w = ev[7]*inv;
    float4* op = (float4*)(out + (size_t)b * 16 + 8);
    op[0] = o0; op[1] = o1;
}

extern "C" void kernel_launch(void* const* d_in, const int* in_sizes, int n_in,
                              void* d_out, int out_size, void* d_ws, size_t ws_size,
                              hipStream_t stream)
{
    const float* x      = (const float*)d_in[0];
    const float* W_root = (const float*)d_in[1];
    const float* b_root = (const float*)d_in[2];
    const float* W_dec  = (const float*)d_in[3];
    const float* b_dec  = (const float*)d_in[4];
    const float* W_leaf = (const float*)d_in[5];
    const float* b_leaf = (const float*)d_in[6];
    const float* W_ldec = (const float*)d_in[7];
    const float* b_ldec = (const float*)d_in[8];
    float* out = (float*)d_out;

    char* w = (char*)d_ws;
    unsigned short* hbuf       = (unsigned short*)(w);               // 67,108,864
    float*          logit_part = (float*)(w + 67108864);             //  8,388,608
    unsigned short* WlT        = (unsigned short*)(w + 75497472);    //  4,194,304
    unsigned short* WldT       = (unsigned short*)(w + 79691776);    //    131,072
    unsigned short* WdT        = (unsigned short*)(w + 79822848);    //     16,384
    float*          ldec_part  = (float*)(w + 79839232);             //  8,388,608
    int*            route      = (int*)(w + 88227840);               //    262,144
    int*            rows_list  = (int*)(w + 88489984);               //    266,240
    unsigned short* WrTh       = (unsigned short*)(w + 88756224);    //    524,288
    int*            rescue     = (int*)(w + 89280512);               //     32,768
    int*            meta       = (int*)(w + 89313280);               //      4,096
    const size_t WS_NEED = 89317376ULL;
    if (ws_size < WS_NEED) return;

    (void)hipMemsetAsync(meta, 0, 4096, stream);

    k_prep   <<<864,  256, 0, stream>>>(W_root, W_leaf, W_ldec, W_dec, WrTh, WlT, WldT, WdT);
    k_root   <<<1024, 512, 0, stream>>>(x, WrTh, b_root, WdT, hbuf, logit_part);
    k_dec    <<<256,  256, 0, stream>>>(logit_part, b_dec, out, route, meta, rescue);
    k_rescue <<<8192, 256, 0, stream>>>(x, W_root, b_root, W_dec, b_dec, rescue, meta, out, route);
    k_scan   <<<1,    64,  0, stream>>>(meta);
    k_scatter<<<256,  256, 0, stream>>>(route, meta, rows_list);
    k_gemm2  <<<2080, 256, 0, stream>>>(hbuf, WlT, b_leaf, WldT, rows_list, meta, ldec_part);
    k_sel    <<<256,  256, 0, stream>>>(ldec_part, route, b_ldec, out);
}

// Round 17
// 247.165 us; speedup vs baseline: 1.2336x; 1.0165x over previous
//
#include <hip/hip_runtime.h>
#include <stdint.h>

#define DD   512
#define EE   8

typedef __bf16 bf16x8 __attribute__((ext_vector_type(8)));
typedef float  f32x4  __attribute__((ext_vector_type(4)));
typedef unsigned short u16x8 __attribute__((ext_vector_type(8)));

__device__ __forceinline__ unsigned short f2bf(float f) {  // RTNE
    union { float f; unsigned int i; } v; v.f = f;
    unsigned int x = v.i;
    x += 0x7fffu + ((x >> 16) & 1u);
    return (unsigned short)(x >> 16);
}
__device__ __forceinline__ void gload_lds16(const void* g, void* l) {
    __builtin_amdgcn_global_load_lds(
        (const __attribute__((address_space(1))) unsigned int*)g,
        (__attribute__((address_space(3))) unsigned int*)l, 16, 0, 0);
}
__device__ __forceinline__ f32x4 mfma_bf16(bf16x8 a, bf16x8 b, f32x4 c) {
    return __builtin_amdgcn_mfma_f32_16x16x32_bf16(a, b, c, 0, 0, 0);
}

// ---------- K0: merged prep — W_root^T, W_leaf^T, W_ldec pad^T, W_dec pad^T ----------
__global__ __launch_bounds__(256) void k_prep(
    const float* __restrict__ W_root, const float* __restrict__ W_leaf,
    const float* __restrict__ W_ldec, const float* __restrict__ W_dec,
    unsigned short* __restrict__ WrTh, unsigned short* __restrict__ WlT,
    unsigned short* __restrict__ WldT, unsigned short* __restrict__ WdT)
{
    __shared__ unsigned short tile[64][65];
    int bid = blockIdx.x;            // 864 = 64 (wtr) + 512 (trW) + 256 (trpad) + 32 (trdec)
    int t = threadIdx.x;
    if (bid < 576) {
        const float* src;
        unsigned short* dst;
        int tl;
        if (bid < 64) {
            src = W_root; dst = WrTh; tl = bid;
        } else {
            int e = (bid - 64) >> 6;
            src = W_leaf + (size_t)e * DD * DD;
            dst = WlT + (size_t)e * DD * DD;
            tl = (bid - 64) & 63;
        }
        int tr = tl >> 3, tc = tl & 7;
        #pragma unroll
        for (int j = 0; j < 16; j++) {
            int i2 = t + j * 256; int r = i2 >> 6, c = i2 & 63;
            tile[r][c] = f2bf(src[(size_t)(tr * 64 + r) * DD + tc * 64 + c]);
        }
        __syncthreads();
        #pragma unroll
        for (int j = 0; j < 16; j++) {
            int i2 = t + j * 256; int r = i2 >> 6, c = i2 & 63;
            dst[(size_t)(tc * 64 + r) * DD + tr * 64 + c] = tile[c][r];
        }
    } else if (bid < 832) {
        int idx = (bid - 576) * 256 + t;           // 65536: WldT [e][16][512]
        int e = idx >> 13, rem = idx & 8191;
        int o = rem >> 9, k = rem & 511;
        unsigned short v = 0;
        if (o < 8) v = f2bf(W_ldec[((size_t)e * DD + k) * EE + o]);
        WldT[idx] = v;
    } else {
        int idx = (bid - 832) * 256 + t;           // 8192: WdT [16][512]
        int o = idx >> 9, k = idx & 511;
        WdT[idx] = (o < 8) ? f2bf(W_dec[(size_t)k * EE + o]) : (unsigned short)0;
    }
}

// ---------- K1: bf16 MFMA root GEMM; BM=256, 512 threads, dbuf single-barrier K-loop ----------
__global__ __launch_bounds__(512) void k_root(
    const float* __restrict__ x,
    const unsigned short* __restrict__ WrTh,
    const float* __restrict__ b_root,
    const unsigned short* __restrict__ WdT,
    unsigned short* __restrict__ hbuf,
    float* __restrict__ logit_part)          // [4][65536][8], p = cb
{
    __shared__ unsigned short smem[40960];       // 81920 B; A dbuf 2x32KB + B dbuf 2x8KB; epi lh[256][136]
    float* fA = (float*)&smem[0];                // f32 buffers at idx 0 / 8192 (256x32 f32 each)
    unsigned short* bB = &smem[32768];           // u16 buffers at idx 0 / 4096 (128x32 bf16 each)

    int bid = blockIdx.x;                         // 1024 = 256 mb * 4 cb
    int mb = (bid >> 5) * 8 + (bid & 7);          // XCD-swizzled
    int cb = (bid >> 3) & 3;
    int m0 = mb * 256, n0 = cb * 128;

    int t = threadIdx.x;
    int wid = t >> 6, lane = t & 63;
    int wr = wid >> 1, wc = wid & 1;              // wr 0..3, wc 0..1
    int l15 = lane & 15, l4 = lane >> 4;

    int arow = t >> 3;                            // 0..63
    int aswz = ((t & 7) ^ (arow & 7)) * 4;
    const float* srcA = x + (size_t)(m0 + arow) * DD + aswz;
    int adst = arow * 32 + aswz;
    const unsigned short* srcB = WrTh + (size_t)(n0 + (t >> 2)) * DD + (t & 3) * 8;

    f32x4 acc[4][4];
    #pragma unroll
    for (int m = 0; m < 4; m++)
        #pragma unroll
        for (int n = 0; n < 4; n++) acc[m][n] = (f32x4){0.f, 0.f, 0.f, 0.f};

    #pragma unroll
    for (int j = 0; j < 4; j++)
        gload_lds16(srcA + (size_t)j * 64 * DD, fA + adst + j * 2048);
    gload_lds16(srcB, bB + t * 8);
    __syncthreads();

    for (int it = 0; it < 16; ++it) {
        int cur = it & 1;
        int ao = cur * 8192;
        int bo = cur * 4096;
        if (it < 15) {
            int k0n = (it + 1) * 32;
            int aon = (cur ^ 1) * 8192, bon = (cur ^ 1) * 4096;
            #pragma unroll
            for (int j = 0; j < 4; j++)
                gload_lds16(srcA + (size_t)j * 64 * DD + k0n, fA + aon + adst + j * 2048);
            gload_lds16(srcB + k0n, bB + bon + t * 8);
        }
        bf16x8 fa[4], fb[4];
        #pragma unroll
        for (int m = 0; m < 4; m++) {
            int r = wr * 64 + m * 16 + l15;
            int s0 = (l4 * 2) ^ (r & 7), s1 = (l4 * 2 + 1) ^ (r & 7);
            f32x4 lo = *(const f32x4*)&fA[ao + r * 32 + s0 * 4];
            f32x4 hi = *(const f32x4*)&fA[ao + r * 32 + s1 * 4];
            #pragma unroll
            for (int j = 0; j < 4; j++) { fa[m][j] = (__bf16)lo[j]; fa[m][4 + j] = (__bf16)hi[j]; }
        }
        #pragma unroll
        for (int n = 0; n < 4; n++)
            fb[n] = *(const bf16x8*)&bB[bo + (wc * 64 + n * 16 + l15) * 32 + l4 * 8];
        #pragma unroll
        for (int m = 0; m < 4; m++)
            #pragma unroll
            for (int n = 0; n < 4; n++)
                acc[m][n] = mfma_bf16(fa[m], fb[n], acc[m][n]);
        __syncthreads();
    }

    float bcol[4];
    #pragma unroll
    for (int n = 0; n < 4; n++) bcol[n] = b_root[n0 + wc * 64 + n * 16 + l15];
    #pragma unroll
    for (int n = 0; n < 4; n++) {
        int coll = wc * 64 + n * 16 + l15;
        #pragma unroll
        for (int m = 0; m < 4; m++) {
            int rl = wr * 64 + m * 16 + l4 * 4;
            #pragma unroll
            for (int i = 0; i < 4; i++) {
                float v = acc[m][n][i] + bcol[n];
                v = v > 0.f ? v : 0.f;
                smem[(rl + i) * 136 + coll] = f2bf(v);
            }
        }
    }
    __syncthreads();

    {
        int r = t >> 1, c0s = (t & 1) * 64;
        unsigned short* dst = hbuf + (size_t)(m0 + r) * DD + n0 + c0s;
        #pragma unroll
        for (int j = 0; j < 8; j++)
            *(u16x8*)(dst + j * 8) = *(const u16x8*)&smem[r * 136 + c0s + j * 8];
    }

    f32x4 acc2[2];
    acc2[0] = (f32x4){0.f, 0.f, 0.f, 0.f};
    acc2[1] = (f32x4){0.f, 0.f, 0.f, 0.f};
    #pragma unroll
    for (int kk = 0; kk < 4; kk++) {
        bf16x8 bb = *(const bf16x8*)(WdT + (size_t)l15 * DD + n0 + kk * 32 + l4 * 8);
        #pragma unroll
        for (int m2 = 0; m2 < 2; m2++) {
            bf16x8 aa = *(const bf16x8*)&smem[(wid * 32 + m2 * 16 + l15) * 136 + kk * 32 + l4 * 8];
            acc2[m2] = mfma_bf16(aa, bb, acc2[m2]);
        }
    }
    if (l15 < 8) {
        #pragma unroll
        for (int m2 = 0; m2 < 2; m2++)
            #pragma unroll
            for (int i = 0; i < 4; i++) {
                int rowg = m0 + wid * 32 + m2 * 16 + l4 * 4 + i;
                logit_part[((size_t)cb * 65536 + rowg) * 8 + l15] = acc2[m2][i];
            }
    }
}

// ---------- K2: dec softmax + route + gap-flag + fused ballot count ----------
__global__ __launch_bounds__(256) void k_dec(
    const float* __restrict__ logit_part,
    const float* __restrict__ b_dec,
    float* __restrict__ out,
    int* __restrict__ route,
    int* __restrict__ meta,
    int* __restrict__ rescue_list)
{
    __shared__ int wcnt[4][8];
    int b = blockIdx.x * 256 + threadIdx.x;
    double lg[8];
    #pragma unroll
    for (int o = 0; o < 8; o++) lg[o] = (double)b_dec[o];
    #pragma unroll
    for (int ppp = 0; ppp < 4; ppp++) {
        #pragma unroll
        for (int o = 0; o < 8; o++)
            lg[o] += (double)logit_part[((size_t)ppp * 65536 + b) * 8 + o];
    }
    double mx = -1e300, mx2 = -1e300; int idx = 0;
    #pragma unroll
    for (int o = 0; o < 8; o++) {
        if (lg[o] > mx) { mx2 = mx; mx = lg[o]; idx = o; }
        else if (lg[o] > mx2) mx2 = lg[o];
    }
    float ev[8], s = 0.f;
    #pragma unroll
    for (int o = 0; o < 8; o++) { ev[o] = expf((float)(lg[o] - mx)); s += ev[o]; }
    float inv = 1.f / s;
    float4 o0, o1;
    o0.x = ev[0]*inv; o0.y = ev[1]*inv; o0.z = ev[2]*inv; o0.w = ev[3]*inv;
    o1.x = ev[4]*inv; o1.y = ev[5]*inv; o1.z = ev[6]*inv; o1.w = ev[7]*inv;
    float4* op = (float4*)(out + (size_t)b * 16);
    op[0] = o0; op[1] = o1;
    route[b] = idx;
    if (mx - mx2 < 3e-3) {
        int pos = atomicAdd(&meta[27], 1);
        if (pos < 8192) rescue_list[pos] = b;
    }
    int lane = threadIdx.x & 63, wv = threadIdx.x >> 6;
    #pragma unroll
    for (int ex = 0; ex < 8; ex++) {
        unsigned long long m = __ballot(idx == ex);
        if (lane == 0) wcnt[wv][ex] = __popcll(m);
    }
    __syncthreads();
    if (threadIdx.x < 8) {
        int ex = threadIdx.x;
        atomicAdd(&meta[ex], wcnt[0][ex] + wcnt[1][ex] + wcnt[2][ex] + wcnt[3][ex]);
    }
}

// ---------- K2b: exact f64 rescue (dec + route + count fixup) ----------
__global__ __launch_bounds__(256) void k_rescue(
    const float* __restrict__ x,
    const float* __restrict__ W_root,
    const float* __restrict__ b_root,
    const float* __restrict__ W_dec,
    const float* __restrict__ b_dec,
    const int* __restrict__ rescue_list,
    int* __restrict__ meta,
    float* __restrict__ out,
    int* __restrict__ route)
{
    int nresc = min(meta[27], 8192);
    if ((int)blockIdx.x >= nresc) return;
    int row = rescue_list[blockIdx.x];
    int t = threadIdx.x;

    __shared__ float xr[512];
    __shared__ double red[4][8];
    xr[t * 2]     = x[(size_t)row * DD + t * 2];
    xr[t * 2 + 1] = x[(size_t)row * DD + t * 2 + 1];
    __syncthreads();

    int d0 = t, d1 = t + 256;
    double a0 = 0.0, a1 = 0.0;
    for (int k = 0; k < DD; k++) {
        double xv = (double)xr[k];
        a0 += xv * (double)W_root[(size_t)k * DD + d0];
        a1 += xv * (double)W_root[(size_t)k * DD + d1];
    }
    double h0 = fmax(a0 + (double)b_root[d0], 0.0);
    double h1 = fmax(a1 + (double)b_root[d1], 0.0);
    double so[8];
    #pragma unroll
    for (int o = 0; o < 8; o++)
        so[o] = h0 * (double)W_dec[d0 * 8 + o] + h1 * (double)W_dec[d1 * 8 + o];
    #pragma unroll
    for (int d = 1; d < 64; d <<= 1)
        #pragma unroll
        for (int o = 0; o < 8; o++) so[o] += __shfl_xor(so[o], d, 64);
    if ((t & 63) == 0) {
        #pragma unroll
        for (int o = 0; o < 8; o++) red[t >> 6][o] = so[o];
    }
    __syncthreads();
    if (t == 0) {
        double lg[8]; double mx = -1e300; int idx = 0;
        #pragma unroll
        for (int o = 0; o < 8; o++) {
            lg[o] = red[0][o] + red[1][o] + red[2][o] + red[3][o] + (double)b_dec[o];
            if (lg[o] > mx) { mx = lg[o]; idx = o; }
        }
        double ev[8], s = 0.0;
        #pragma unroll
        for (int o = 0; o < 8; o++) { ev[o] = exp(lg[o] - mx); s += ev[o]; }
        double inv = 1.0 / s;
        float4 o0, o1;
        o0.x = (float)(ev[0]*inv); o0.y = (float)(ev[1]*inv);
        o0.z = (float)(ev[2]*inv); o0.w = (float)(ev[3]*inv);
        o1.x = (float)(ev[4]*inv); o1.y = (float)(ev[5]*inv);
        o1.z = (float)(ev[6]*inv); o1.w = (float)(ev[7]*inv);
        float4* op = (float4*)(out + (size_t)row * 16);
        op[0] = o0; op[1] = o1;
        int old = route[row];
        if (idx != old) {
            atomicSub(&meta[old], 1);
            atomicAdd(&meta[idx], 1);
            route[row] = idx;
        }
    }
}

// ---------- K3: scan (256-row padding) ----------
__global__ void k_scan(int* __restrict__ meta)
{
    if (threadIdx.x == 0 && blockIdx.x == 0) {
        int run = 0, rb = 0;
        for (int e = 0; e < 8; e++) {
            int c = meta[e];
            meta[16 + e] = run;
            meta[8 + e]  = run;
            int n = (c + 255) >> 8;
            for (int j = 0; j < n; j++) meta[32 + rb + j] = e | (j << 8);
            rb += n;
            run += n << 8;
        }
        meta[24] = rb;
    }
}

// ---------- K4: scatter — ballot-ranked, 8 atomics/block ----------
__global__ __launch_bounds__(256) void k_scatter(
    const int* __restrict__ route, int* __restrict__ meta, int* __restrict__ rows_list)
{
    __shared__ int wcnt[4][8];
    __shared__ int wbase[4][8];
    int b = blockIdx.x * 256 + threadIdx.x;
    int e = route[b];
    int lane = threadIdx.x & 63, wv = threadIdx.x >> 6;
    unsigned long long mymask = 0;
    #pragma unroll
    for (int ex = 0; ex < 8; ex++) {
        unsigned long long m = __ballot(e == ex);
        if (e == ex) mymask = m;
        if (lane == 0) wcnt[wv][ex] = __popcll(m);
    }
    int myrank = __popcll(mymask & ((1ULL << lane) - 1ULL));
    __syncthreads();
    if (threadIdx.x < 8) {
        int ex = threadIdx.x;
        int c0 = wcnt[0][ex], c1 = wcnt[1][ex], c2 = wcnt[2][ex], c3 = wcnt[3][ex];
        int base = atomicAdd(&meta[8 + ex], c0 + c1 + c2 + c3);
        wbase[0][ex] = base;
        wbase[1][ex] = base + c0;
        wbase[2][ex] = base + c0 + c1;
        wbase[3][ex] = base + c0 + c1 + c2;
    }
    __syncthreads();
    rows_list[wbase[wv][e] + myrank] = b;
}

// ---------- K5: grouped leaf GEMM; BM=256, 512 threads, dbuf single-barrier K-loop ----------
__global__ __launch_bounds__(512) void k_gemm2(
    const unsigned short* __restrict__ hbuf,
    const unsigned short* __restrict__ WlT,
    const float* __restrict__ b_leaf,
    const unsigned short* __restrict__ WldT,
    const int* __restrict__ rows_list,
    const int* __restrict__ meta,
    float* __restrict__ ldec_part)           // [4][65536][8]
{
    __shared__ unsigned short smem[34816];       // 69632 B; loop: A dbuf 2x16KB + B dbuf 2x8KB; epi lh[256][136]
    // A buffers: u16 idx 0 / 8192 (256x32 each); B buffers: u16 idx 16384 / 20480 (128x32 each)

    int bid = blockIdx.x;                        // 1088 = 272 rb * 4 cb (swizzled)
    int rbid = (bid >> 5) * 8 + (bid & 7);
    int cb = (bid >> 3) & 3;
    if (rbid >= meta[24]) return;
    int pk = meta[32 + rbid];
    int e = pk & 255, lrb = pk >> 8;
    int poff_e = meta[16 + e], cnt_e = meta[e];
    int n0 = cb * 128;

    int t = threadIdx.x;
    int wid = t >> 6, lane = t & 63;
    int wr = wid >> 1, wc = wid & 1;             // wr 0..3, wc 0..1
    int l15 = lane & 15, l4 = lane >> 4;

    int slot0 = poff_e + lrb * 256 + (t >> 2);
    int slot1 = slot0 + 128;
    int lastv = poff_e + cnt_e - 1;
    int grow0 = rows_list[min(slot0, lastv)];    // clamp pad slots (idempotent recompute)
    int grow1 = rows_list[min(slot1, lastv)];
    const unsigned short* srcA0 = hbuf + (size_t)grow0 * DD + (t & 3) * 8;
    const unsigned short* srcA1 = hbuf + (size_t)grow1 * DD + (t & 3) * 8;
    const unsigned short* srcB  = WlT + (size_t)e * DD * DD + (size_t)(n0 + (t >> 2)) * DD + (t & 3) * 8;

    f32x4 acc[4][4];
    #pragma unroll
    for (int m = 0; m < 4; m++)
        #pragma unroll
        for (int n = 0; n < 4; n++) acc[m][n] = (f32x4){0.f, 0.f, 0.f, 0.f};

    // prologue: stage tile 0 into buffer 0
    gload_lds16(srcA0, &smem[t * 8]);
    gload_lds16(srcA1, &smem[4096 + t * 8]);
    gload_lds16(srcB,  &smem[16384 + t * 8]);
    __syncthreads();

    for (int it = 0; it < 16; ++it) {
        int cur = it & 1;
        int ao = cur * 8192, bo = 16384 + cur * 4096;
        if (it < 15) {
            int k0n = (it + 1) * 32;
            int aon = (cur ^ 1) * 8192, bon = 16384 + (cur ^ 1) * 4096;
            gload_lds16(srcA0 + k0n, &smem[aon + t * 8]);
            gload_lds16(srcA1 + k0n, &smem[aon + 4096 + t * 8]);
            gload_lds16(srcB + k0n,  &smem[bon + t * 8]);
        }
        bf16x8 af[4], bfr[4];
        #pragma unroll
        for (int m = 0; m < 4; m++)
            af[m] = *(const bf16x8*)&smem[ao + (wr * 64 + m * 16 + l15) * 32 + l4 * 8];
        #pragma unroll
        for (int n = 0; n < 4; n++)
            bfr[n] = *(const bf16x8*)&smem[bo + (wc * 64 + n * 16 + l15) * 32 + l4 * 8];
        #pragma unroll
        for (int m = 0; m < 4; m++)
            #pragma unroll
            for (int n = 0; n < 4; n++)
                acc[m][n] = mfma_bf16(af[m], bfr[n], acc[m][n]);
        __syncthreads();
    }

    // epilogue 1: bias + relu -> lh tile (bf16) in smem [256][136]
    float bcol[4];
    #pragma unroll
    for (int n = 0; n < 4; n++) bcol[n] = b_leaf[(size_t)e * DD + n0 + wc * 64 + n * 16 + l15];
    #pragma unroll
    for (int n = 0; n < 4; n++) {
        int coll = wc * 64 + n * 16 + l15;
        #pragma unroll
        for (int m = 0; m < 4; m++) {
            int rl = wr * 64 + m * 16 + l4 * 4;
            #pragma unroll
            for (int i = 0; i < 4; i++) {
                float v = acc[m][n][i] + bcol[n];
                v = v > 0.f ? v : 0.f;
                smem[(rl + i) * 136 + coll] = f2bf(v);
            }
        }
    }
    __syncthreads();

    // epilogue 2: ldec partial = lh_tile @ W_ldec[e][n0:n0+128][:] via MFMA (8 waves x 32 rows)
    f32x4 acc2[2];
    acc2[0] = (f32x4){0.f, 0.f, 0.f, 0.f};
    acc2[1] = (f32x4){0.f, 0.f, 0.f, 0.f};
    #pragma unroll
    for (int kk = 0; kk < 4; kk++) {
        bf16x8 bb = *(const bf16x8*)(WldT + ((size_t)e * 16 + l15) * DD + n0 + kk * 32 + l4 * 8);
        #pragma unroll
        for (int m2 = 0; m2 < 2; m2++) {
            bf16x8 aa = *(const bf16x8*)&smem[(wid * 32 + m2 * 16 + l15) * 136 + kk * 32 + l4 * 8];
            acc2[m2] = mfma_bf16(aa, bb, acc2[m2]);
        }
    }
    if (l15 < 8) {
        #pragma unroll
        for (int m2 = 0; m2 < 2; m2++)
            #pragma unroll
            for (int i = 0; i < 4; i++) {
                int rl = wid * 32 + m2 * 16 + l4 * 4 + i;
                int s = min(poff_e + lrb * 256 + rl, lastv);
                int brow = rows_list[s];             // pad slots: duplicate identical writes
                ldec_part[((size_t)cb * 65536 + brow) * 8 + l15] = acc2[m2][i];
            }
    }
}

// ---------- K6: sel softmax ----------
__global__ __launch_bounds__(256) void k_sel(
    const float* __restrict__ ldec_part,
    const int* __restrict__ route,
    const float* __restrict__ b_ldec,
    float* __restrict__ out)
{
    int b = blockIdx.x * 256 + threadIdx.x;
    int e = route[b];
    float lg[8];
    #pragma unroll
    for (int o = 0; o < 8; o++) lg[o] = b_ldec[e * 8 + o];
    #pragma unroll
    for (int p = 0; p < 4; p++) {
        const float4* ap = (const float4*)(ldec_part + ((size_t)p * 65536 + b) * 8);
        float4 a0 = ap[0], a1 = ap[1];
        lg[0]+=a0.x; lg[1]+=a0.y; lg[2]+=a0.z; lg[3]+=a0.w;
        lg[4]+=a1.x; lg[5]+=a1.y; lg[6]+=a1.z; lg[7]+=a1.w;
    }
    float mx = -1e30f;
    #pragma unroll
    for (int o = 0; o < 8; o++) mx = fmaxf(mx, lg[o]);
    float ev[8], s = 0.f;
    #pragma unroll
    for (int o = 0; o < 8; o++) { ev[o] = expf(lg[o] - mx); s += ev[o]; }
    float inv = 1.f / s;
    float4 o0, o1;
    o0.x = ev[0]*inv; o0.y = ev[1]*inv; o0.z = ev[2]*inv; o0.w = ev[3]*inv;
    o1.x = ev[4]*inv; o1.y = ev[5]*inv; o1.z = ev[6]*inv; o1.w = ev[7]*inv;
    float4* op = (float4*)(out + (size_t)b * 16 + 8);
    op[0] = o0; op[1] = o1;
}

extern "C" void kernel_launch(void* const* d_in, const int* in_sizes, int n_in,
                              void* d_out, int out_size, void* d_ws, size_t ws_size,
                              hipStream_t stream)
{
    const float* x      = (const float*)d_in[0];
    const float* W_root = (const float*)d_in[1];
    const float* b_root = (const float*)d_in[2];
    const float* W_dec  = (const float*)d_in[3];
    const float* b_dec  = (const float*)d_in[4];
    const float* W_leaf = (const float*)d_in[5];
    const float* b_leaf = (const float*)d_in[6];
    const float* W_ldec = (const float*)d_in[7];
    const float* b_ldec = (const float*)d_in[8];
    float* out = (float*)d_out;

    char* w = (char*)d_ws;
    unsigned short* hbuf       = (unsigned short*)(w);               // 67,108,864
    float*          logit_part = (float*)(w + 67108864);             //  8,388,608
    unsigned short* WlT        = (unsigned short*)(w + 75497472);    //  4,194,304
    unsigned short* WldT       = (unsigned short*)(w + 79691776);    //    131,072
    unsigned short* WdT        = (unsigned short*)(w + 79822848);    //     16,384
    float*          ldec_part  = (float*)(w + 79839232);             //  8,388,608
    int*            route      = (int*)(w + 88227840);               //    262,144
    int*            rows_list  = (int*)(w + 88489984);               //    273,408 (68352 ints; 256-pad bound 67576)
    unsigned short* WrTh       = (unsigned short*)(w + 88763392);    //    524,288
    int*            rescue     = (int*)(w + 89287680);               //     32,768
    int*            meta       = (int*)(w + 89320448);               //      4,096
    const size_t WS_NEED = 89324544ULL;
    if (ws_size < WS_NEED) return;

    (void)hipMemsetAsync(meta, 0, 4096, stream);

    k_prep   <<<864,  256, 0, stream>>>(W_root, W_leaf, W_ldec, W_dec, WrTh, WlT, WldT, WdT);
    k_root   <<<1024, 512, 0, stream>>>(x, WrTh, b_root, WdT, hbuf, logit_part);
    k_dec    <<<256,  256, 0, stream>>>(logit_part, b_dec, out, route, meta, rescue);
    k_rescue <<<8192, 256, 0, stream>>>(x, W_root, b_root, W_dec, b_dec, rescue, meta, out, route);
    k_scan   <<<1,    64,  0, stream>>>(meta);
    k_scatter<<<256,  256, 0, stream>>>(route, meta, rows_list);
    k_gemm2  <<<1088, 512, 0, stream>>>(hbuf, WlT, b_leaf, WldT, rows_list, meta, ldec_part);
    k_sel    <<<256,  256, 0, stream>>>(ldec_part, route, b_ldec, out);
}